// Round 8
// baseline (192.659 us; speedup 1.0000x reference)
//
#include <hip/hip_runtime.h>

typedef __bf16 bf16_t;
typedef __bf16 bf16x4 __attribute__((ext_vector_type(4)));
typedef __bf16 bf16x8 __attribute__((ext_vector_type(8)));
typedef float f32x4 __attribute__((ext_vector_type(4)));
typedef unsigned int u32x2 __attribute__((ext_vector_type(2)));
typedef unsigned long long u64;

#define MFMA16(a, b, c) __builtin_amdgcn_mfma_f32_16x16x32_bf16((a), (b), (c), 0, 0, 0)

#define LDG2LDS16(g, l)                                                        \
    __builtin_amdgcn_global_load_lds(                                          \
        (const __attribute__((address_space(1))) void*)(g),                    \
        (__attribute__((address_space(3))) void*)(l), 16, 0, 0)

#if __has_builtin(__builtin_amdgcn_exp2f)
#define EXP2(x) __builtin_amdgcn_exp2f(x)
#else
#define EXP2(x) exp2f(x)
#endif

// load 8 consecutive fp32 as bf16x8
__device__ inline bf16x8 load8(const float* p) {
    const f32x4 a = *(const f32x4*)p;
    const f32x4 b = *(const f32x4*)(p + 4);
    bf16x8 r;
#pragma unroll
    for (int i = 0; i < 4; i++) { r[i] = (bf16_t)a[i]; r[4 + i] = (bf16_t)b[i]; }
    return r;
}

__device__ inline u32x2 as2(bf16x4 v) {
    u32x2 r;
    __builtin_memcpy(&r, &v, 8);
    return r;
}

// 8-byte cross-lane shuffle of a packed bf16x4 (fallback path)
__device__ inline bf16x4 shfl4(bf16x4 v, int src) {
    u64 x;
    __builtin_memcpy(&x, &v, 8);
    x = __shfl(x, src, 64);
    bf16x4 r;
    __builtin_memcpy(&r, &x, 8);
    return r;
}

// P C-layout (two bf16x4 regs covering 32 keys) -> PV B-fragment, via 6
// permlane swaps (verified algebra, rounds 0-7), ds_bpermute fallback.
__device__ inline bf16x8 p2pf(bf16x4 pb0, bf16x4 pb1, int quad, int lr) {
    bf16x8 pf;
#if __has_builtin(__builtin_amdgcn_permlane16_swap) && \
    __has_builtin(__builtin_amdgcn_permlane32_swap)
    const u32x2 P0 = as2(pb0);
    const u32x2 P1 = as2(pb1);
    const u32x2 s1a = __builtin_amdgcn_permlane16_swap(P0[0], P0[1], false, false);
    const u32x2 s1b = __builtin_amdgcn_permlane16_swap(P1[0], P1[1], false, false);
    const u32x2 s2a = __builtin_amdgcn_permlane32_swap(s1a[0], s1b[0], false, false);
    const u32x2 s2b = __builtin_amdgcn_permlane32_swap(s1a[1], s1b[1], false, false);
    const u32x2 s3a = __builtin_amdgcn_permlane16_swap(s2a[0], s2a[1], false, false);
    const u32x2 s3b = __builtin_amdgcn_permlane16_swap(s2b[0], s2b[1], false, false);
    const unsigned pfd[4] = {s3a[0], s3a[1], s3b[0], s3b[1]};
    __builtin_memcpy(&pf, pfd, 16);
#else
    const int srcLow = ((quad & 1) << 5) + lr;
    const int srcHigh = srcLow + 16;
    const bool loSel = (quad < 2);
    const bf16x4 a0 = shfl4(pb0, srcLow);
    const bf16x4 a1 = shfl4(pb1, srcLow);
    const bf16x4 b0 = shfl4(pb0, srcHigh);
    const bf16x4 b1 = shfl4(pb1, srcHigh);
    const bf16x4 lo = loSel ? a0 : a1;
    const bf16x4 hi = loSel ? b0 : b1;
#pragma unroll
    for (int r = 0; r < 4; r++) { pf[r] = lo[r]; pf[4 + r] = hi[r]; }
#endif
    return pf;
}

// ---------------------------------------------------------------------------
// fp32 -> bf16 convert: hs (4194304 el) | wqkv (3145728 el) | wo (1048576 el)
// ---------------------------------------------------------------------------
__global__ __launch_bounds__(256) void convert_kernel(const float* __restrict__ hs,
                                                      const float* __restrict__ wqkv,
                                                      const float* __restrict__ wo,
                                                      bf16_t* __restrict__ outb) {
    const size_t c = ((size_t)blockIdx.x * 256 + threadIdx.x) * 8;
    const float* src;
    size_t off;
    if (c < 4194304) { src = hs; off = c; }
    else if (c < 7340032) { src = wqkv; off = c - 4194304; }
    else { src = wo; off = c - 7340032; }
    *(bf16x8*)(outb + c) = load8(src + off);
}

// ---------------------------------------------------------------------------
// K/V swizzled layouts (MFMA-fragment order -> attn loads are base+lane*16):
//   k_sw: ((bh*128 + t>>4)*2 + (d>>5))*512 + ((t&15)+16*((d&31)>>3))*8 + (d&7)
//   v_sw: ((bh*64 + t>>5)*4 + (d>>4))*512 + ((d&15)+16*((t&31)>>3))*8 + (t&7)
// For a fixed 64-key tile kb, each of K/V occupies a CONTIGUOUS 4096-el (8 KB)
// region at base + kb*4096 -> stageable with 2 global_load_lds sweeps.
// ---------------------------------------------------------------------------

// ---------------------------------------------------------------------------
// GEMM (m97 structure, BK=32 — best measured 48.3us) + T2 XOR swizzle
// (conflicts measured 0).
// ---------------------------------------------------------------------------
template <int MODE, int NDIM, int BM>
__global__ __launch_bounds__(256) void gemm_bt(const bf16_t* __restrict__ A,
                                               const bf16_t* __restrict__ B,
                                               float* __restrict__ outp,
                                               bf16_t* __restrict__ q_ws,
                                               bf16_t* __restrict__ k_ws,
                                               bf16_t* __restrict__ v_ws,
                                               const float* __restrict__ cosb,
                                               const float* __restrict__ sinb) {
    constexpr int K = 1024;
    constexpr int IM = BM / 32;
    __shared__ __align__(16) bf16_t As[BM * 32];
    __shared__ __align__(16) bf16_t Bs[128 * 32];

    const int tid = threadIdx.x;
    const int w = tid >> 6;
    const int lane = tid & 63;
    const int lr = lane & 15;
    const int quad = lane >> 4;
    const int m0 = blockIdx.y * BM;
    const int n0 = blockIdx.x * 128;
    const int wm = (w & 1) * (BM / 2);
    const int wn = (w >> 1) * 64;

    const int srow = tid >> 2;
    // source slot pre-swizzled: slot ^ f(row), f(row) = (row>>1)&3
    const int skk = (((tid & 3) ^ ((tid >> 3) & 3)) * 8);
    const bf16_t* gA0 = A + (size_t)(m0 + srow) * K + skk;
    const bf16_t* gA1 = gA0 + (size_t)64 * K;
    const bf16_t* gB0 = B + (size_t)(n0 + srow) * K + skk;
    const bf16_t* gB1 = gB0 + (size_t)64 * K;
    bf16_t* lA0 = As + w * 512;
    bf16_t* lA1 = As + 2048 + w * 512;
    bf16_t* lB0 = Bs + w * 512;
    bf16_t* lB1 = Bs + 2048 + w * 512;

    // fragment-read slot: quad ^ f(row); row low bits = lr -> f = (lr>>1)&3
    const int qsw = (quad ^ ((lr >> 1) & 3)) * 8;

    f32x4 acc[IM][4] = {};

    for (int k0 = 0; k0 < K; k0 += 32) {
        LDG2LDS16(gA0 + k0, lA0);
        if constexpr (BM == 128) LDG2LDS16(gA1 + k0, lA1);
        LDG2LDS16(gB0 + k0, lB0);
        LDG2LDS16(gB1 + k0, lB1);
        __syncthreads();

        bf16x8 af[IM], bfm[4];
#pragma unroll
        for (int im = 0; im < IM; im++)
            af[im] = *(const bf16x8*)&As[(wm + im * 16 + lr) * 32 + qsw];
#pragma unroll
        for (int in = 0; in < 4; in++)
            bfm[in] = *(const bf16x8*)&Bs[(wn + in * 16 + lr) * 32 + qsw];
#pragma unroll
        for (int im = 0; im < IM; im++)
#pragma unroll
            for (int in = 0; in < 4; in++)
                acc[im][in] = MFMA16(af[im], bfm[in], acc[im][in]);
        __syncthreads();
    }

    if constexpr (MODE == 0) {
#pragma unroll
        for (int im = 0; im < IM; im++)
#pragma unroll
            for (int in = 0; in < 4; in++)
#pragma unroll
                for (int r = 0; r < 4; r++) {
                    const int m = m0 + wm + im * 16 + quad * 4 + r;
                    const int n = n0 + wn + in * 16 + lr;
                    outp[(size_t)m * NDIM + n] = acc[im][in][r];
                }
    } else {
        const int j = (n0 + wn) >> 6;
        if (j < 32) {
            const bool isq = (j < 16);
            const float qs = 0.125f * 1.44269504089f;
#pragma unroll
            for (int im = 0; im < IM; im++) {
#pragma unroll
                for (int r = 0; r < 4; r++) {
                    const int m = m0 + wm + im * 16 + quad * 4 + r;
                    const int b = m >> 11;
                    const int t = m & 2047;
#pragma unroll
                    for (int in = 0; in < 2; in++) {
                        const int d = in * 16 + lr;
                        const float x1 = acc[im][in][r];
                        const float x2 = acc[im][in + 2][r];
                        const float c = cosb[t * 64 + d];
                        const float s = sinb[t * 64 + d];
                        float y1 = x1 * c - x2 * s;
                        float y2 = x2 * c + x1 * s;
                        if (isq) {
                            y1 *= qs; y2 *= qs;
                            const size_t base =
                                ((size_t)(b * 16 + j) * 2048 + t) * 64 + d;
                            q_ws[base] = (bf16_t)y1;
                            q_ws[base + 32] = (bf16_t)y2;
                        } else {
                            const int bh = b * 16 + (j - 16);
                            const size_t off =
                                ((size_t)(bh * 128 + (t >> 4)) * 2) * 512 +
                                ((t & 15) + (d >> 3) * 16) * 8 + (d & 7);
                            k_ws[off] = (bf16_t)y1;
                            k_ws[off + 512] = (bf16_t)y2;
                        }
                    }
                }
            }
        } else {
#pragma unroll
            for (int im = 0; im < IM; im++)
#pragma unroll
                for (int in = 0; in < 4; in++)
#pragma unroll
                    for (int r = 0; r < 4; r++) {
                        const int m = m0 + wm + im * 16 + quad * 4 + r;
                        const int b = m >> 11;
                        const int t = m & 2047;
                        const int d = in * 16 + lr;
                        const int bh = b * 16 + (j - 32);
                        const size_t off =
                            ((size_t)(bh * 64 + (t >> 5)) * 4 + (d >> 4)) * 512 +
                            ((d & 15) + ((t & 31) >> 3) * 16) * 8 + (t & 7);
                        v_ws[off] = (bf16_t)acc[im][in][r];
                    }
        }
    }
}

// ---------------------------------------------------------------------------
// Flash attention (round 8): MERGED halves. Each WG handles qtA = pr and
// qtB = 31-pr in ONE kb-loop: K fragments are read from LDS once per tile and
// feed QK^T for BOTH query sets (2 MFMA per fragment); same for V in PV.
// For kb <= qtA the tile's LDS reads + staging are amortized 2x -> per-WG
// tile traffic drops 33 -> 32-pr (avg 24.5, -26%), one prologue drain.
// Complementary pr-fold for load balance: pr(p) + pr(p+8) = 15, so
// within-XCD-adjacent blocks (stride 8) pair long+short WGs (reads sum 49).
// Sync skeleton identical to round 7 (hardware-verified): stage(kb+1) at loop
// top into other buffer, compute(kb), lgkmcnt(0)+vmcnt(0)+s_barrier.
// ---------------------------------------------------------------------------
__global__ __launch_bounds__(256) void attn_kernel(const bf16_t* __restrict__ q_ws,
                                                   const bf16_t* __restrict__ k_ws,
                                                   const bf16_t* __restrict__ v_ws,
                                                   bf16_t* __restrict__ ctx) {
    __shared__ __align__(16) bf16_t Ks[2][4096];  // 2 x 8 KB
    __shared__ __align__(16) bf16_t Vs[2][4096];  // 2 x 8 KB

    const int tid = threadIdx.x;
    const int w = tid >> 6;
    const int lane = tid & 63;
    const int lr = lane & 15;
    const int quad = lane >> 4;
    const int bh = blockIdx.x >> 4;               // 0..31
    const int p = blockIdx.x & 15;
    const int pr = (p < 8) ? p : 23 - p;          // pr(p)+pr(p+8) = 15
    const int qtA = pr;                           // 0..15
    const int qtB = 31 - pr;                      // 16..31
    const int b = bh >> 4;
    const int hd = bh & 15;

    const bf16_t* kws = k_ws + (size_t)bh * 131072;
    const bf16_t* vws = v_ws + (size_t)bh * 131072;
    const int soff = w * 512 + lane * 8;  // per-lane element offset in a sweep
    const int lo8 = lane * 8;

#define ASTAGE(kb, buf)                                                        \
    {                                                                          \
        LDG2LDS16(kws + (size_t)(kb) * 4096 + soff, &Ks[buf][w * 512]);        \
        LDG2LDS16(kws + (size_t)(kb) * 4096 + 2048 + soff,                     \
                  &Ks[buf][2048 + w * 512]);                                   \
        LDG2LDS16(vws + (size_t)(kb) * 4096 + soff, &Vs[buf][w * 512]);        \
        LDG2LDS16(vws + (size_t)(kb) * 4096 + 2048 + soff,                     \
                  &Vs[buf][2048 + w * 512]);                                   \
    }

    const int queryA = qtA * 64 + w * 16 + lr;
    const int queryB = qtB * 64 + w * 16 + lr;

    const bf16_t* qbA = q_ws + ((size_t)bh * 2048 + queryA) * 64 + quad * 8;
    const bf16_t* qbB = q_ws + ((size_t)bh * 2048 + queryB) * 64 + quad * 8;
    const bf16x8 qloA = *(const bf16x8*)qbA;
    const bf16x8 qhiA = *(const bf16x8*)(qbA + 32);
    const bf16x8 qloB = *(const bf16x8*)qbB;
    const bf16x8 qhiB = *(const bf16x8*)(qbB + 32);

    f32x4 oA[4] = {}, oB[4] = {};
    float lrA = 0.0f, lrB = 0.0f;

    // prologue: stage tile 0
    ASTAGE(0, 0);
    asm volatile("s_waitcnt vmcnt(0)" ::: "memory");
    __builtin_amdgcn_s_barrier();
    asm volatile("" ::: "memory");

    for (int kb = 0; kb <= qtB; kb++) {
        const int buf = kb & 1;
        if (kb < qtB) ASTAGE(kb + 1, buf ^ 1);

        const bool actA = (kb <= qtA);  // wave-uniform
        const int u0 = kb * 64;

        // K fragments once; 2 QK^T uses each
        bf16x8 kf[8];
#pragma unroll
        for (int n = 0; n < 4; n++) {
            kf[2 * n] = *(const bf16x8*)&Ks[buf][(2 * n) * 512 + lo8];
            kf[2 * n + 1] = *(const bf16x8*)&Ks[buf][(2 * n + 1) * 512 + lo8];
        }

        f32x4 sB[4];
#pragma unroll
        for (int n = 0; n < 4; n++) {
            const f32x4 z = {};
            sB[n] = MFMA16(kf[2 * n], qloB, z);
            sB[n] = MFMA16(kf[2 * n + 1], qhiB, sB[n]);
        }
        f32x4 sA[4];
        if (actA) {
#pragma unroll
            for (int n = 0; n < 4; n++) {
                const f32x4 z = {};
                sA[n] = MFMA16(kf[2 * n], qloA, z);
                sA[n] = MFMA16(kf[2 * n + 1], qhiA, sA[n]);
            }
        }

        if (kb == qtB) {  // diagonal of B
#pragma unroll
            for (int n = 0; n < 4; n++)
#pragma unroll
                for (int r = 0; r < 4; r++)
                    if (u0 + n * 16 + quad * 4 + r > queryB) sB[n][r] = -1e9f;
        }
        if (kb == qtA) {  // diagonal of A
#pragma unroll
            for (int n = 0; n < 4; n++)
#pragma unroll
                for (int r = 0; r < 4; r++)
                    if (u0 + n * 16 + quad * 4 + r > queryA) sA[n][r] = -1e9f;
        }

        bf16x4 pbB[4], pbA[4];
        {
            f32x4 pB[4];
#pragma unroll
            for (int n = 0; n < 4; n++)
#pragma unroll
                for (int r = 0; r < 4; r++) pB[n][r] = EXP2(sB[n][r]);
            lrB += ((pB[0][0] + pB[0][1]) + (pB[0][2] + pB[0][3])) +
                   ((pB[1][0] + pB[1][1]) + (pB[1][2] + pB[1][3])) +
                   ((pB[2][0] + pB[2][1]) + (pB[2][2] + pB[2][3])) +
                   ((pB[3][0] + pB[3][1]) + (pB[3][2] + pB[3][3]));
#pragma unroll
            for (int n = 0; n < 4; n++)
#pragma unroll
                for (int r = 0; r < 4; r++) pbB[n][r] = (bf16_t)pB[n][r];
        }
        if (actA) {
            f32x4 pA[4];
#pragma unroll
            for (int n = 0; n < 4; n++)
#pragma unroll
                for (int r = 0; r < 4; r++) pA[n][r] = EXP2(sA[n][r]);
            lrA += ((pA[0][0] + pA[0][1]) + (pA[0][2] + pA[0][3])) +
                   ((pA[1][0] + pA[1][1]) + (pA[1][2] + pA[1][3])) +
                   ((pA[2][0] + pA[2][1]) + (pA[2][2] + pA[2][3])) +
                   ((pA[3][0] + pA[3][1]) + (pA[3][2] + pA[3][3]));
#pragma unroll
            for (int n = 0; n < 4; n++)
#pragma unroll
                for (int r = 0; r < 4; r++) pbA[n][r] = (bf16_t)pA[n][r];
        }

#pragma unroll
        for (int hh = 0; hh < 2; hh++) {  // 32-key halves
            const bf16x8 pfB = p2pf(pbB[2 * hh], pbB[2 * hh + 1], quad, lr);
            bf16x8 pfA;
            if (actA) pfA = p2pf(pbA[2 * hh], pbA[2 * hh + 1], quad, lr);
#pragma unroll
            for (int n = 0; n < 4; n++) {
                const bf16x8 vvf =
                    *(const bf16x8*)&Vs[buf][(hh * 4 + n) * 512 + lo8];
                oB[n] = MFMA16(vvf, pfB, oB[n]);
                if (actA) oA[n] = MFMA16(vvf, pfA, oA[n]);
            }
        }

        // all LDS reads of buf done; this wave's stage loads landed
        asm volatile("s_waitcnt lgkmcnt(0) vmcnt(0)" ::: "memory");
        __builtin_amdgcn_s_barrier();
        asm volatile("" ::: "memory");
    }

    // epilogue: both query sets
    lrA += __shfl_xor(lrA, 16);
    lrA += __shfl_xor(lrA, 32);
    lrB += __shfl_xor(lrB, 16);
    lrB += __shfl_xor(lrB, 32);

    const float invA = 1.0f / fmaxf(lrA, 1e-30f);
    const float invB = 1.0f / fmaxf(lrB, 1e-30f);
    const size_t baseA = ((size_t)b * 2048 + queryA) * 1024 + hd * 64 + quad * 4;
    const size_t baseB = ((size_t)b * 2048 + queryB) * 1024 + hd * 64 + quad * 4;
#pragma unroll
    for (int n = 0; n < 4; n++) {
        bf16x4 obA, obB;
#pragma unroll
        for (int r = 0; r < 4; r++) {
            obA[r] = (bf16_t)(oA[n][r] * invA);
            obB[r] = (bf16_t)(oB[n][r] * invB);
        }
        *(bf16x4*)&ctx[baseA + n * 16] = obA;
        *(bf16x4*)&ctx[baseB + n * 16] = obB;
    }
#undef ASTAGE
}

// ---------------------------------------------------------------------------
// Launcher. Inputs fp32, output fp32.
// ws bytes: [0,8M) hs_b -> (after gemm1) ctx overlay | [8M,14M) wqkv_b |
//           [14M,16M) wo_b | [16M,24M) q | [24M,32M) k | [32M,40M) v.
// ---------------------------------------------------------------------------
extern "C" void kernel_launch(void* const* d_in, const int* in_sizes, int n_in,
                              void* d_out, int out_size, void* d_ws, size_t ws_size,
                              hipStream_t stream) {
    const float* hs = (const float*)d_in[0];
    const float* cosb = (const float*)d_in[1];
    const float* sinb = (const float*)d_in[2];
    const float* wqkv = (const float*)d_in[3];
    const float* wo = (const float*)d_in[4];
    float* out = (float*)d_out;

    char* ws = (char*)d_ws;
    bf16_t* hs_b = (bf16_t*)(ws);
    bf16_t* wqkv_b = hs_b + 4194304;
    bf16_t* wo_b = hs_b + 7340032;
    bf16_t* q_ws = (bf16_t*)(ws + (size_t)(16u << 20));
    bf16_t* k_ws = (bf16_t*)(ws + (size_t)(24u << 20));
    bf16_t* v_ws = (bf16_t*)(ws + (size_t)(32u << 20));
    bf16_t* ctx = (bf16_t*)(ws);  // overlays hs_b (dead after gemm1)

    const dim3 blk(256);

    // 0) fp32 -> bf16 convert (hs | wqkv | wo packed)
    convert_kernel<<<dim3(4096), blk, 0, stream>>>(hs, wqkv, wo, hs_b);

    // 1) QKV projection + fused RoPE + scatter: M=4096, N=3072, K=1024
    gemm_bt<1, 3072, 128><<<dim3(24, 32), blk, 0, stream>>>(
        hs_b, wqkv_b, nullptr, q_ws, k_ws, v_ws, cosb, sinb);

    // 2) Flash attention (merged halves, LDS-shared K/V) -> ctx (bf16)
    attn_kernel<<<dim3(512), blk, 0, stream>>>(q_ws, k_ws, v_ws, ctx);

    // 3) Output projection: M=4096, N=1024, K=1024 (BM=64 -> 512 blocks)
    gemm_bt<0, 1024, 64><<<dim3(8, 64), blk, 0, stream>>>(
        ctx, wo_b, out, nullptr, nullptr, nullptr, nullptr, nullptr);
}

// Round 9
// 176.051 us; speedup vs baseline: 1.0943x; 1.0943x over previous
//
#include <hip/hip_runtime.h>

typedef __bf16 bf16_t;
typedef __bf16 bf16x4 __attribute__((ext_vector_type(4)));
typedef __bf16 bf16x8 __attribute__((ext_vector_type(8)));
typedef float f32x4 __attribute__((ext_vector_type(4)));
typedef unsigned int u32x2 __attribute__((ext_vector_type(2)));
typedef unsigned long long u64;

#define MFMA16(a, b, c) __builtin_amdgcn_mfma_f32_16x16x32_bf16((a), (b), (c), 0, 0, 0)

#define LDG2LDS16(g, l)                                                        \
    __builtin_amdgcn_global_load_lds(                                          \
        (const __attribute__((address_space(1))) void*)(g),                    \
        (__attribute__((address_space(3))) void*)(l), 16, 0, 0)

#if __has_builtin(__builtin_amdgcn_exp2f)
#define EXP2(x) __builtin_amdgcn_exp2f(x)
#else
#define EXP2(x) exp2f(x)
#endif

// load 8 consecutive fp32 as bf16x8
__device__ inline bf16x8 load8(const float* p) {
    const f32x4 a = *(const f32x4*)p;
    const f32x4 b = *(const f32x4*)(p + 4);
    bf16x8 r;
#pragma unroll
    for (int i = 0; i < 4; i++) { r[i] = (bf16_t)a[i]; r[4 + i] = (bf16_t)b[i]; }
    return r;
}

__device__ inline u32x2 as2(bf16x4 v) {
    u32x2 r;
    __builtin_memcpy(&r, &v, 8);
    return r;
}

// 8-byte cross-lane shuffle of a packed bf16x4 (fallback path)
__device__ inline bf16x4 shfl4(bf16x4 v, int src) {
    u64 x;
    __builtin_memcpy(&x, &v, 8);
    x = __shfl(x, src, 64);
    bf16x4 r;
    __builtin_memcpy(&r, &x, 8);
    return r;
}

// ---------------------------------------------------------------------------
// fp32 -> bf16 convert: hs (4194304 el) | wqkv (3145728 el) | wo (1048576 el)
// ---------------------------------------------------------------------------
__global__ __launch_bounds__(256) void convert_kernel(const float* __restrict__ hs,
                                                      const float* __restrict__ wqkv,
                                                      const float* __restrict__ wo,
                                                      bf16_t* __restrict__ outb) {
    const size_t c = ((size_t)blockIdx.x * 256 + threadIdx.x) * 8;
    const float* src;
    size_t off;
    if (c < 4194304) { src = hs; off = c; }
    else if (c < 7340032) { src = wqkv; off = c - 4194304; }
    else { src = wo; off = c - 7340032; }
    *(bf16x8*)(outb + c) = load8(src + off);
}

// ---------------------------------------------------------------------------
// K/V swizzled layouts (MFMA-fragment order -> attn loads are base+lane*16):
//   k_sw: ((bh*128 + t>>4)*2 + (d>>5))*512 + ((t&15)+16*((d&31)>>3))*8 + (d&7)
//   v_sw: ((bh*64 + t>>5)*4 + (d>>4))*512 + ((d&15)+16*((t&31)>>3))*8 + (t&7)
// For a fixed 64-key tile kb, each of K/V occupies a CONTIGUOUS 4096-el (8 KB)
// region at base + kb*4096 -> stageable with 2 global_load_lds sweeps.
// ---------------------------------------------------------------------------

// ---------------------------------------------------------------------------
// GEMM (m97 structure, BK=32 — best measured 48.3us) + T2 XOR swizzle
// (conflicts measured 0).
// ---------------------------------------------------------------------------
template <int MODE, int NDIM, int BM>
__global__ __launch_bounds__(256) void gemm_bt(const bf16_t* __restrict__ A,
                                               const bf16_t* __restrict__ B,
                                               float* __restrict__ outp,
                                               bf16_t* __restrict__ q_ws,
                                               bf16_t* __restrict__ k_ws,
                                               bf16_t* __restrict__ v_ws,
                                               const float* __restrict__ cosb,
                                               const float* __restrict__ sinb) {
    constexpr int K = 1024;
    constexpr int IM = BM / 32;
    __shared__ __align__(16) bf16_t As[BM * 32];
    __shared__ __align__(16) bf16_t Bs[128 * 32];

    const int tid = threadIdx.x;
    const int w = tid >> 6;
    const int lane = tid & 63;
    const int lr = lane & 15;
    const int quad = lane >> 4;
    const int m0 = blockIdx.y * BM;
    const int n0 = blockIdx.x * 128;
    const int wm = (w & 1) * (BM / 2);
    const int wn = (w >> 1) * 64;

    const int srow = tid >> 2;
    // source slot pre-swizzled: slot ^ f(row), f(row) = (row>>1)&3
    const int skk = (((tid & 3) ^ ((tid >> 3) & 3)) * 8);
    const bf16_t* gA0 = A + (size_t)(m0 + srow) * K + skk;
    const bf16_t* gA1 = gA0 + (size_t)64 * K;
    const bf16_t* gB0 = B + (size_t)(n0 + srow) * K + skk;
    const bf16_t* gB1 = gB0 + (size_t)64 * K;
    bf16_t* lA0 = As + w * 512;
    bf16_t* lA1 = As + 2048 + w * 512;
    bf16_t* lB0 = Bs + w * 512;
    bf16_t* lB1 = Bs + 2048 + w * 512;

    // fragment-read slot: quad ^ f(row); row low bits = lr -> f = (lr>>1)&3
    const int qsw = (quad ^ ((lr >> 1) & 3)) * 8;

    f32x4 acc[IM][4] = {};

    for (int k0 = 0; k0 < K; k0 += 32) {
        LDG2LDS16(gA0 + k0, lA0);
        if constexpr (BM == 128) LDG2LDS16(gA1 + k0, lA1);
        LDG2LDS16(gB0 + k0, lB0);
        LDG2LDS16(gB1 + k0, lB1);
        __syncthreads();

        bf16x8 af[IM], bfm[4];
#pragma unroll
        for (int im = 0; im < IM; im++)
            af[im] = *(const bf16x8*)&As[(wm + im * 16 + lr) * 32 + qsw];
#pragma unroll
        for (int in = 0; in < 4; in++)
            bfm[in] = *(const bf16x8*)&Bs[(wn + in * 16 + lr) * 32 + qsw];
#pragma unroll
        for (int im = 0; im < IM; im++)
#pragma unroll
            for (int in = 0; in < 4; in++)
                acc[im][in] = MFMA16(af[im], bfm[in], acc[im][in]);
        __syncthreads();
    }

    if constexpr (MODE == 0) {
#pragma unroll
        for (int im = 0; im < IM; im++)
#pragma unroll
            for (int in = 0; in < 4; in++)
#pragma unroll
                for (int r = 0; r < 4; r++) {
                    const int m = m0 + wm + im * 16 + quad * 4 + r;
                    const int n = n0 + wn + in * 16 + lr;
                    outp[(size_t)m * NDIM + n] = acc[im][in][r];
                }
    } else {
        const int j = (n0 + wn) >> 6;
        if (j < 32) {
            const bool isq = (j < 16);
            const float qs = 0.125f * 1.44269504089f;
#pragma unroll
            for (int im = 0; im < IM; im++) {
#pragma unroll
                for (int r = 0; r < 4; r++) {
                    const int m = m0 + wm + im * 16 + quad * 4 + r;
                    const int b = m >> 11;
                    const int t = m & 2047;
#pragma unroll
                    for (int in = 0; in < 2; in++) {
                        const int d = in * 16 + lr;
                        const float x1 = acc[im][in][r];
                        const float x2 = acc[im][in + 2][r];
                        const float c = cosb[t * 64 + d];
                        const float s = sinb[t * 64 + d];
                        float y1 = x1 * c - x2 * s;
                        float y2 = x2 * c + x1 * s;
                        if (isq) {
                            y1 *= qs; y2 *= qs;
                            const size_t base =
                                ((size_t)(b * 16 + j) * 2048 + t) * 64 + d;
                            q_ws[base] = (bf16_t)y1;
                            q_ws[base + 32] = (bf16_t)y2;
                        } else {
                            const int bh = b * 16 + (j - 16);
                            const size_t off =
                                ((size_t)(bh * 128 + (t >> 4)) * 2) * 512 +
                                ((t & 15) + (d >> 3) * 16) * 8 + (d & 7);
                            k_ws[off] = (bf16_t)y1;
                            k_ws[off + 512] = (bf16_t)y2;
                        }
                    }
                }
            }
        } else {
#pragma unroll
            for (int im = 0; im < IM; im++)
#pragma unroll
                for (int in = 0; in < 4; in++)
#pragma unroll
                    for (int r = 0; r < 4; r++) {
                        const int m = m0 + wm + im * 16 + quad * 4 + r;
                        const int b = m >> 11;
                        const int t = m & 2047;
                        const int d = in * 16 + lr;
                        const int bh = b * 16 + (j - 32);
                        const size_t off =
                            ((size_t)(bh * 64 + (t >> 5)) * 4 + (d >> 4)) * 512 +
                            ((d & 15) + ((t & 31) >> 3) * 16) * 8 + (t & 7);
                        v_ws[off] = (bf16_t)acc[im][in][r];
                    }
        }
    }
}

// ---------------------------------------------------------------------------
// Flash attention (round 9): round-7 per-iteration body and sync skeleton,
// UNMERGED, with the grid split 2x finer for occupancy: WG = (bh, qt) with
// 1024 WGs (4 WGs/CU -> up to 16 waves/CU vs round 7's 8; attn measured
// latency/VALU-bound at Occupancy 18%, VALUBusy 52%, MfmaUtil 12%).
// - bh = blockIdx&31 KEPT: each XCD sees only 4 bh K/V streams (2 MB,
//   L2-resident). Round 8's bh=blockIdx>>4 thrashed L2 (FETCH 70 MB).
// - qt dispatch order alternates long/short (g even -> 31-g/2, g odd -> g/2)
//   so long WGs start first and per-CU work sums balance.
// Total staged tiles unchanged vs round 7 (sum(qt+1) over qt = 528 = 16.5avg
// x 32 = same 33/WG-pair). Sync: stage(kb+1) at loop top into other buffer,
// compute(kb), lgkmcnt(0)+vmcnt(0)+s_barrier (hardware-verified r7).
// ---------------------------------------------------------------------------
__global__ __launch_bounds__(256) void attn_kernel(const bf16_t* __restrict__ q_ws,
                                                   const bf16_t* __restrict__ k_ws,
                                                   const bf16_t* __restrict__ v_ws,
                                                   bf16_t* __restrict__ ctx) {
    __shared__ __align__(16) bf16_t Ks[2][4096];  // 2 x 8 KB
    __shared__ __align__(16) bf16_t Vs[2][4096];  // 2 x 8 KB

    const int tid = threadIdx.x;
    const int w = tid >> 6;
    const int lane = tid & 63;
    const int lr = lane & 15;
    const int quad = lane >> 4;
    const int bh = blockIdx.x & 31;
    const int g = blockIdx.x >> 5;                  // 0..31
    const int qt = (g & 1) ? (g >> 1) : (31 - (g >> 1));  // bijective 0..31
    const int b = bh >> 4;
    const int hd = bh & 15;

    const bf16_t* kws = k_ws + (size_t)bh * 131072;
    const bf16_t* vws = v_ws + (size_t)bh * 131072;
    const int soff = w * 512 + lane * 8;  // per-lane element offset in a sweep
    const int lo8 = lane * 8;

    // stage one 64-key K+V tile (8 KB each) into buf: 4 global_load_lds calls
#define ASTAGE(kb, buf)                                                        \
    {                                                                          \
        LDG2LDS16(kws + (size_t)(kb) * 4096 + soff, &Ks[buf][w * 512]);        \
        LDG2LDS16(kws + (size_t)(kb) * 4096 + 2048 + soff,                     \
                  &Ks[buf][2048 + w * 512]);                                   \
        LDG2LDS16(vws + (size_t)(kb) * 4096 + soff, &Vs[buf][w * 512]);        \
        LDG2LDS16(vws + (size_t)(kb) * 4096 + 2048 + soff,                     \
                  &Vs[buf][2048 + w * 512]);                                   \
    }

    const int trow = qt * 64 + w * 16;
    const int query = trow + lr;

    const bf16_t* qb = q_ws + ((size_t)bh * 2048 + trow + lr) * 64 + quad * 8;
    const bf16x8 qlo = *(const bf16x8*)qb;
    const bf16x8 qhi = *(const bf16x8*)(qb + 32);

    f32x4 o[4] = {};
    float lrun = 0.0f;

    // prologue: stage tile 0
    ASTAGE(0, 0);
    asm volatile("s_waitcnt vmcnt(0)" ::: "memory");
    __builtin_amdgcn_s_barrier();
    asm volatile("" ::: "memory");

    for (int kb = 0; kb <= qt; kb++) {
        const int buf = kb & 1;
        if (kb < qt) ASTAGE(kb + 1, buf ^ 1);

        // ---- QK^T from LDS ----
        f32x4 s[4];
#pragma unroll
        for (int n = 0; n < 4; n++) {
            const bf16x8 k0 = *(const bf16x8*)&Ks[buf][(2 * n) * 512 + lo8];
            const bf16x8 k1 = *(const bf16x8*)&Ks[buf][(2 * n + 1) * 512 + lo8];
            const f32x4 z = {};
            s[n] = MFMA16(k0, qlo, z);
            s[n] = MFMA16(k1, qhi, s[n]);
        }

        const int u0 = kb * 64;
        if (kb == qt) {  // diagonal: causal mask (key > query)
#pragma unroll
            for (int n = 0; n < 4; n++)
#pragma unroll
                for (int r = 0; r < 4; r++)
                    if (u0 + n * 16 + quad * 4 + r > query) s[n][r] = -1e9f;
        }

        f32x4 p[4];
#pragma unroll
        for (int n = 0; n < 4; n++)
#pragma unroll
            for (int r = 0; r < 4; r++) p[n][r] = EXP2(s[n][r]);

        lrun += ((p[0][0] + p[0][1]) + (p[0][2] + p[0][3])) +
                ((p[1][0] + p[1][1]) + (p[1][2] + p[1][3])) +
                ((p[2][0] + p[2][1]) + (p[2][2] + p[2][3])) +
                ((p[3][0] + p[3][1]) + (p[3][2] + p[3][3]));

        bf16x4 pb[4];
#pragma unroll
        for (int n = 0; n < 4; n++)
#pragma unroll
            for (int r = 0; r < 4; r++) pb[n][r] = (bf16_t)p[n][r];

#pragma unroll
        for (int hh = 0; hh < 2; hh++) {  // 32-key halves
            bf16x8 pf;
#if __has_builtin(__builtin_amdgcn_permlane16_swap) && \
    __has_builtin(__builtin_amdgcn_permlane32_swap)
            const u32x2 P0 = as2(pb[2 * hh]);
            const u32x2 P1 = as2(pb[2 * hh + 1]);
            const u32x2 s1a = __builtin_amdgcn_permlane16_swap(P0[0], P0[1], false, false);
            const u32x2 s1b = __builtin_amdgcn_permlane16_swap(P1[0], P1[1], false, false);
            const u32x2 s2a = __builtin_amdgcn_permlane32_swap(s1a[0], s1b[0], false, false);
            const u32x2 s2b = __builtin_amdgcn_permlane32_swap(s1a[1], s1b[1], false, false);
            const u32x2 s3a = __builtin_amdgcn_permlane16_swap(s2a[0], s2a[1], false, false);
            const u32x2 s3b = __builtin_amdgcn_permlane16_swap(s2b[0], s2b[1], false, false);
            const unsigned pfd[4] = {s3a[0], s3a[1], s3b[0], s3b[1]};
            __builtin_memcpy(&pf, pfd, 16);
#else
            const int srcLow = ((quad & 1) << 5) + lr;
            const int srcHigh = srcLow + 16;
            const bool loSel = (quad < 2);
            const bf16x4 a0 = shfl4(pb[2 * hh], srcLow);
            const bf16x4 a1 = shfl4(pb[2 * hh + 1], srcLow);
            const bf16x4 b0 = shfl4(pb[2 * hh], srcHigh);
            const bf16x4 b1 = shfl4(pb[2 * hh + 1], srcHigh);
            const bf16x4 lo = loSel ? a0 : a1;
            const bf16x4 hi = loSel ? b0 : b1;
#pragma unroll
            for (int r = 0; r < 4; r++) { pf[r] = lo[r]; pf[4 + r] = hi[r]; }
#endif
#pragma unroll
            for (int n = 0; n < 4; n++) {
                const bf16x8 vvf =
                    *(const bf16x8*)&Vs[buf][(hh * 4 + n) * 512 + lo8];
                o[n] = MFMA16(vvf, pf, o[n]);
            }
        }

        // all LDS reads of buf done; this wave's stage loads landed
        asm volatile("s_waitcnt lgkmcnt(0) vmcnt(0)" ::: "memory");
        __builtin_amdgcn_s_barrier();
        asm volatile("" ::: "memory");
    }

    lrun += __shfl_xor(lrun, 16);
    lrun += __shfl_xor(lrun, 32);

    const float inv = 1.0f / fmaxf(lrun, 1e-30f);
    const size_t base = ((size_t)b * 2048 + query) * 1024 + hd * 64 + quad * 4;
#pragma unroll
    for (int n = 0; n < 4; n++) {
        bf16x4 ob;
#pragma unroll
        for (int r = 0; r < 4; r++) ob[r] = (bf16_t)(o[n][r] * inv);
        *(bf16x4*)&ctx[base + n * 16] = ob;
    }
#undef ASTAGE
}

// ---------------------------------------------------------------------------
// Launcher. Inputs fp32, output fp32.
// ws bytes: [0,8M) hs_b -> (after gemm1) ctx overlay | [8M,14M) wqkv_b |
//           [14M,16M) wo_b | [16M,24M) q | [24M,32M) k | [32M,40M) v.
// ---------------------------------------------------------------------------
extern "C" void kernel_launch(void* const* d_in, const int* in_sizes, int n_in,
                              void* d_out, int out_size, void* d_ws, size_t ws_size,
                              hipStream_t stream) {
    const float* hs = (const float*)d_in[0];
    const float* cosb = (const float*)d_in[1];
    const float* sinb = (const float*)d_in[2];
    const float* wqkv = (const float*)d_in[3];
    const float* wo = (const float*)d_in[4];
    float* out = (float*)d_out;

    char* ws = (char*)d_ws;
    bf16_t* hs_b = (bf16_t*)(ws);
    bf16_t* wqkv_b = hs_b + 4194304;
    bf16_t* wo_b = hs_b + 7340032;
    bf16_t* q_ws = (bf16_t*)(ws + (size_t)(16u << 20));
    bf16_t* k_ws = (bf16_t*)(ws + (size_t)(24u << 20));
    bf16_t* v_ws = (bf16_t*)(ws + (size_t)(32u << 20));
    bf16_t* ctx = (bf16_t*)(ws);  // overlays hs_b (dead after gemm1)

    const dim3 blk(256);

    // 0) fp32 -> bf16 convert (hs | wqkv | wo packed)
    convert_kernel<<<dim3(4096), blk, 0, stream>>>(hs, wqkv, wo, hs_b);

    // 1) QKV projection + fused RoPE + scatter: M=4096, N=3072, K=1024
    gemm_bt<1, 3072, 128><<<dim3(24, 32), blk, 0, stream>>>(
        hs_b, wqkv_b, nullptr, q_ws, k_ws, v_ws, cosb, sinb);

    // 2) Flash attention (1024 WGs, one qt each, LDS-shared K/V) -> ctx (bf16)
    attn_kernel<<<dim3(1024), blk, 0, stream>>>(q_ws, k_ws, v_ws, ctx);

    // 3) Output projection: M=4096, N=1024, K=1024 (BM=64 -> 512 blocks)
    gemm_bt<0, 1024, 64><<<dim3(8, 64), blk, 0, stream>>>(
        ctx, wo_b, out, nullptr, nullptr, nullptr, nullptr, nullptr);
}

// Round 10
// 174.086 us; speedup vs baseline: 1.1067x; 1.0113x over previous
//
#include <hip/hip_runtime.h>

typedef __bf16 bf16_t;
typedef __bf16 bf16x4 __attribute__((ext_vector_type(4)));
typedef __bf16 bf16x8 __attribute__((ext_vector_type(8)));
typedef float f32x4 __attribute__((ext_vector_type(4)));
typedef unsigned int u32x2 __attribute__((ext_vector_type(2)));
typedef unsigned long long u64;

#define MFMA16(a, b, c) __builtin_amdgcn_mfma_f32_16x16x32_bf16((a), (b), (c), 0, 0, 0)

#define LDG2LDS16(g, l)                                                        \
    __builtin_amdgcn_global_load_lds(                                          \
        (const __attribute__((address_space(1))) void*)(g),                    \
        (__attribute__((address_space(3))) void*)(l), 16, 0, 0)

#if __has_builtin(__builtin_amdgcn_exp2f)
#define EXP2(x) __builtin_amdgcn_exp2f(x)
#else
#define EXP2(x) exp2f(x)
#endif

// load 8 consecutive fp32 as bf16x8
__device__ inline bf16x8 load8(const float* p) {
    const f32x4 a = *(const f32x4*)p;
    const f32x4 b = *(const f32x4*)(p + 4);
    bf16x8 r;
#pragma unroll
    for (int i = 0; i < 4; i++) { r[i] = (bf16_t)a[i]; r[4 + i] = (bf16_t)b[i]; }
    return r;
}

__device__ inline u32x2 as2(bf16x4 v) {
    u32x2 r;
    __builtin_memcpy(&r, &v, 8);
    return r;
}

// 8-byte cross-lane shuffle of a packed bf16x4 (fallback path)
__device__ inline bf16x4 shfl4(bf16x4 v, int src) {
    u64 x;
    __builtin_memcpy(&x, &v, 8);
    x = __shfl(x, src, 64);
    bf16x4 r;
    __builtin_memcpy(&r, &x, 8);
    return r;
}

// ---------------------------------------------------------------------------
// fp32 -> bf16 convert: hs (4194304 el) | wqkv (3145728 el) | wo (1048576 el)
// ---------------------------------------------------------------------------
__global__ __launch_bounds__(256) void convert_kernel(const float* __restrict__ hs,
                                                      const float* __restrict__ wqkv,
                                                      const float* __restrict__ wo,
                                                      bf16_t* __restrict__ outb) {
    const size_t c = ((size_t)blockIdx.x * 256 + threadIdx.x) * 8;
    const float* src;
    size_t off;
    if (c < 4194304) { src = hs; off = c; }
    else if (c < 7340032) { src = wqkv; off = c - 4194304; }
    else { src = wo; off = c - 7340032; }
    *(bf16x8*)(outb + c) = load8(src + off);
}

// ---------------------------------------------------------------------------
// K/V swizzled layouts (MFMA-fragment order -> attn loads are base+lane*16):
//   k_sw: ((bh*128 + t>>4)*2 + (d>>5))*512 + ((t&15)+16*((d&31)>>3))*8 + (d&7)
//   v_sw: ((bh*64 + t>>5)*4 + (d>>4))*512 + ((d&15)+16*((t&31)>>3))*8 + (t&7)
// For a fixed 64-key tile kb, each of K/V occupies a CONTIGUOUS 4096-el (8 KB)
// region at base + kb*4096 -> stageable with 2 global_load_lds sweeps.
// ---------------------------------------------------------------------------

// ---------------------------------------------------------------------------
// GEMM (m97 structure, BK=32 — best measured 48.3us) + T2 XOR swizzle
// (conflicts measured 0).
// ---------------------------------------------------------------------------
template <int MODE, int NDIM, int BM>
__global__ __launch_bounds__(256) void gemm_bt(const bf16_t* __restrict__ A,
                                               const bf16_t* __restrict__ B,
                                               float* __restrict__ outp,
                                               bf16_t* __restrict__ q_ws,
                                               bf16_t* __restrict__ k_ws,
                                               bf16_t* __restrict__ v_ws,
                                               const float* __restrict__ cosb,
                                               const float* __restrict__ sinb) {
    constexpr int K = 1024;
    constexpr int IM = BM / 32;
    __shared__ __align__(16) bf16_t As[BM * 32];
    __shared__ __align__(16) bf16_t Bs[128 * 32];

    const int tid = threadIdx.x;
    const int w = tid >> 6;
    const int lane = tid & 63;
    const int lr = lane & 15;
    const int quad = lane >> 4;
    const int m0 = blockIdx.y * BM;
    const int n0 = blockIdx.x * 128;
    const int wm = (w & 1) * (BM / 2);
    const int wn = (w >> 1) * 64;

    const int srow = tid >> 2;
    // source slot pre-swizzled: slot ^ f(row), f(row) = (row>>1)&3
    const int skk = (((tid & 3) ^ ((tid >> 3) & 3)) * 8);
    const bf16_t* gA0 = A + (size_t)(m0 + srow) * K + skk;
    const bf16_t* gA1 = gA0 + (size_t)64 * K;
    const bf16_t* gB0 = B + (size_t)(n0 + srow) * K + skk;
    const bf16_t* gB1 = gB0 + (size_t)64 * K;
    bf16_t* lA0 = As + w * 512;
    bf16_t* lA1 = As + 2048 + w * 512;
    bf16_t* lB0 = Bs + w * 512;
    bf16_t* lB1 = Bs + 2048 + w * 512;

    // fragment-read slot: quad ^ f(row); row low bits = lr -> f = (lr>>1)&3
    const int qsw = (quad ^ ((lr >> 1) & 3)) * 8;

    f32x4 acc[IM][4] = {};

    for (int k0 = 0; k0 < K; k0 += 32) {
        LDG2LDS16(gA0 + k0, lA0);
        if constexpr (BM == 128) LDG2LDS16(gA1 + k0, lA1);
        LDG2LDS16(gB0 + k0, lB0);
        LDG2LDS16(gB1 + k0, lB1);
        __syncthreads();

        bf16x8 af[IM], bfm[4];
#pragma unroll
        for (int im = 0; im < IM; im++)
            af[im] = *(const bf16x8*)&As[(wm + im * 16 + lr) * 32 + qsw];
#pragma unroll
        for (int in = 0; in < 4; in++)
            bfm[in] = *(const bf16x8*)&Bs[(wn + in * 16 + lr) * 32 + qsw];
#pragma unroll
        for (int im = 0; im < IM; im++)
#pragma unroll
            for (int in = 0; in < 4; in++)
                acc[im][in] = MFMA16(af[im], bfm[in], acc[im][in]);
        __syncthreads();
    }

    if constexpr (MODE == 0) {
#pragma unroll
        for (int im = 0; im < IM; im++)
#pragma unroll
            for (int in = 0; in < 4; in++)
#pragma unroll
                for (int r = 0; r < 4; r++) {
                    const int m = m0 + wm + im * 16 + quad * 4 + r;
                    const int n = n0 + wn + in * 16 + lr;
                    outp[(size_t)m * NDIM + n] = acc[im][in][r];
                }
    } else {
        const int j = (n0 + wn) >> 6;
        if (j < 32) {
            const bool isq = (j < 16);
            const float qs = 0.125f * 1.44269504089f;
#pragma unroll
            for (int im = 0; im < IM; im++) {
#pragma unroll
                for (int r = 0; r < 4; r++) {
                    const int m = m0 + wm + im * 16 + quad * 4 + r;
                    const int b = m >> 11;
                    const int t = m & 2047;
#pragma unroll
                    for (int in = 0; in < 2; in++) {
                        const int d = in * 16 + lr;
                        const float x1 = acc[im][in][r];
                        const float x2 = acc[im][in + 2][r];
                        const float c = cosb[t * 64 + d];
                        const float s = sinb[t * 64 + d];
                        float y1 = x1 * c - x2 * s;
                        float y2 = x2 * c + x1 * s;
                        if (isq) {
                            y1 *= qs; y2 *= qs;
                            const size_t base =
                                ((size_t)(b * 16 + j) * 2048 + t) * 64 + d;
                            q_ws[base] = (bf16_t)y1;
                            q_ws[base + 32] = (bf16_t)y2;
                        } else {
                            const int bh = b * 16 + (j - 16);
                            const size_t off =
                                ((size_t)(bh * 128 + (t >> 4)) * 2) * 512 +
                                ((t & 15) + (d >> 3) * 16) * 8 + (d & 7);
                            k_ws[off] = (bf16_t)y1;
                            k_ws[off + 512] = (bf16_t)y2;
                        }
                    }
                }
            }
        } else {
#pragma unroll
            for (int im = 0; im < IM; im++)
#pragma unroll
                for (int in = 0; in < 4; in++)
#pragma unroll
                    for (int r = 0; r < 4; r++) {
                        const int m = m0 + wm + im * 16 + quad * 4 + r;
                        const int b = m >> 11;
                        const int t = m & 2047;
                        const int d = in * 16 + lr;
                        const int bh = b * 16 + (j - 32);
                        const size_t off =
                            ((size_t)(bh * 64 + (t >> 5)) * 4 + (d >> 4)) * 512 +
                            ((d & 15) + ((t & 31) >> 3) * 16) * 8 + (t & 7);
                        v_ws[off] = (bf16_t)acc[im][in][r];
                    }
        }
    }
}

// ---------------------------------------------------------------------------
// Flash attention (round 10): round-7 structure (paired halves, 512 WGs,
// bh=blockIdx&31 -> 4 bh streams/XCD L2-resident, LDS-shared K/V) with the
// double buffer upgraded to a TRIPLE buffer + counted vmcnt(4) (T4):
//   iter kb: issue stage(kb+2) -> buf (kb+2)%3 ; compute buf kb%3 ;
//            lgkmcnt(0) + vmcnt(4) + s_barrier
// The newest 4 loads stay in flight across the barrier; the tile needed next
// iteration has had 2 full compute phases to land (r8 profile: ~35% of attn
// time was the unattributed drain/barrier stall; VALU 52%, MFMA 12%).
// Buffer-overwrite safety = same barrier argument as the verified r7 code:
// the last read of buf (kb+2)%3 was iter kb-1, sealed by lgkmcnt(0)+barrier
// before the stage issues. LDS 48 KB/WG keeps 2 WGs/CU.
// Math, masking, permlane algebra, outputs: byte-identical to round 7.
// ---------------------------------------------------------------------------
__global__ __launch_bounds__(256) void attn_kernel(const bf16_t* __restrict__ q_ws,
                                                   const bf16_t* __restrict__ k_ws,
                                                   const bf16_t* __restrict__ v_ws,
                                                   bf16_t* __restrict__ ctx) {
    __shared__ __align__(16) bf16_t Ks[3][4096];  // 3 x 8 KB
    __shared__ __align__(16) bf16_t Vs[3][4096];  // 3 x 8 KB

    const int tid = threadIdx.x;
    const int w = tid >> 6;
    const int lane = tid & 63;
    const int lr = lane & 15;
    const int quad = lane >> 4;
    const int bh = blockIdx.x & 31;
    const int pr = blockIdx.x >> 5;  // 0..15
    const int b = bh >> 4;
    const int hd = bh & 15;

    const bf16_t* kws = k_ws + (size_t)bh * 131072;
    const bf16_t* vws = v_ws + (size_t)bh * 131072;
    const int soff = w * 512 + lane * 8;  // per-lane element offset in a sweep
    const int lo8 = lane * 8;

    // stage one 64-key K+V tile (8 KB each) into buf: 4 global_load_lds calls
#define ASTAGE(kb, buf)                                                        \
    {                                                                          \
        LDG2LDS16(kws + (size_t)(kb) * 4096 + soff, &Ks[buf][w * 512]);        \
        LDG2LDS16(kws + (size_t)(kb) * 4096 + 2048 + soff,                     \
                  &Ks[buf][2048 + w * 512]);                                   \
        LDG2LDS16(vws + (size_t)(kb) * 4096 + soff, &Vs[buf][w * 512]);        \
        LDG2LDS16(vws + (size_t)(kb) * 4096 + 2048 + soff,                     \
                  &Vs[buf][2048 + w * 512]);                                   \
    }

#pragma unroll
    for (int half = 0; half < 2; half++) {
        const int qt = half ? (31 - pr) : pr;
        const int trow = qt * 64 + w * 16;
        const int query = trow + lr;

        const bf16_t* qb = q_ws + ((size_t)bh * 2048 + trow + lr) * 64 + quad * 8;
        const bf16x8 qlo = *(const bf16x8*)qb;
        const bf16x8 qhi = *(const bf16x8*)(qb + 32);

        f32x4 o[4] = {};
        float lrun = 0.0f;

        // prologue: stage tiles 0 (and 1 if present); wait tile 0 (counted)
        ASTAGE(0, 0);
        if (qt >= 1) {
            ASTAGE(1, 1);
            asm volatile("s_waitcnt vmcnt(4)" ::: "memory");
        } else {
            asm volatile("s_waitcnt vmcnt(0)" ::: "memory");
        }
        __builtin_amdgcn_s_barrier();
        asm volatile("" ::: "memory");

        for (int kb = 0; kb <= qt; kb++) {
            const int buf = kb % 3;
            const bool more = (kb + 2 <= qt);  // block-uniform
            if (more) ASTAGE(kb + 2, (kb + 2) % 3);

            // ---- QK^T from LDS ----
            f32x4 s[4];
#pragma unroll
            for (int n = 0; n < 4; n++) {
                const bf16x8 k0 = *(const bf16x8*)&Ks[buf][(2 * n) * 512 + lo8];
                const bf16x8 k1 = *(const bf16x8*)&Ks[buf][(2 * n + 1) * 512 + lo8];
                const f32x4 z = {};
                s[n] = MFMA16(k0, qlo, z);
                s[n] = MFMA16(k1, qhi, s[n]);
            }

            const int u0 = kb * 64;
            if (kb == qt) {  // diagonal: causal mask (key > query)
#pragma unroll
                for (int n = 0; n < 4; n++)
#pragma unroll
                    for (int r = 0; r < 4; r++)
                        if (u0 + n * 16 + quad * 4 + r > query) s[n][r] = -1e9f;
            }

            f32x4 p[4];
#pragma unroll
            for (int n = 0; n < 4; n++)
#pragma unroll
                for (int r = 0; r < 4; r++) p[n][r] = EXP2(s[n][r]);

            lrun += ((p[0][0] + p[0][1]) + (p[0][2] + p[0][3])) +
                    ((p[1][0] + p[1][1]) + (p[1][2] + p[1][3])) +
                    ((p[2][0] + p[2][1]) + (p[2][2] + p[2][3])) +
                    ((p[3][0] + p[3][1]) + (p[3][2] + p[3][3]));

            bf16x4 pb[4];
#pragma unroll
            for (int n = 0; n < 4; n++)
#pragma unroll
                for (int r = 0; r < 4; r++) pb[n][r] = (bf16_t)p[n][r];

#pragma unroll
            for (int hh = 0; hh < 2; hh++) {  // 32-key halves
                bf16x8 pf;
#if __has_builtin(__builtin_amdgcn_permlane16_swap) && \
    __has_builtin(__builtin_amdgcn_permlane32_swap)
                const u32x2 P0 = as2(pb[2 * hh]);
                const u32x2 P1 = as2(pb[2 * hh + 1]);
                const u32x2 s1a = __builtin_amdgcn_permlane16_swap(P0[0], P0[1], false, false);
                const u32x2 s1b = __builtin_amdgcn_permlane16_swap(P1[0], P1[1], false, false);
                const u32x2 s2a = __builtin_amdgcn_permlane32_swap(s1a[0], s1b[0], false, false);
                const u32x2 s2b = __builtin_amdgcn_permlane32_swap(s1a[1], s1b[1], false, false);
                const u32x2 s3a = __builtin_amdgcn_permlane16_swap(s2a[0], s2a[1], false, false);
                const u32x2 s3b = __builtin_amdgcn_permlane16_swap(s2b[0], s2b[1], false, false);
                const unsigned pfd[4] = {s3a[0], s3a[1], s3b[0], s3b[1]};
                __builtin_memcpy(&pf, pfd, 16);
#else
                const int srcLow = ((quad & 1) << 5) + lr;
                const int srcHigh = srcLow + 16;
                const bool loSel = (quad < 2);
                const bf16x4 a0 = shfl4(pb[2 * hh], srcLow);
                const bf16x4 a1 = shfl4(pb[2 * hh + 1], srcLow);
                const bf16x4 b0 = shfl4(pb[2 * hh], srcHigh);
                const bf16x4 b1 = shfl4(pb[2 * hh + 1], srcHigh);
                const bf16x4 lo = loSel ? a0 : a1;
                const bf16x4 hi = loSel ? b0 : b1;
#pragma unroll
                for (int r = 0; r < 4; r++) { pf[r] = lo[r]; pf[4 + r] = hi[r]; }
#endif
#pragma unroll
                for (int n = 0; n < 4; n++) {
                    const bf16x8 vvf =
                        *(const bf16x8*)&Vs[buf][(hh * 4 + n) * 512 + lo8];
                    o[n] = MFMA16(vvf, pf, o[n]);
                }
            }

            // reads of buf done (lgkm); tile kb+1 landed (vmcnt counted) —
            // tile kb+2's 4 loads stay in flight across the barrier.
            if (more) {
                asm volatile("s_waitcnt lgkmcnt(0) vmcnt(4)" ::: "memory");
            } else {
                asm volatile("s_waitcnt lgkmcnt(0) vmcnt(0)" ::: "memory");
            }
            __builtin_amdgcn_s_barrier();
            asm volatile("" ::: "memory");
        }

        lrun += __shfl_xor(lrun, 16);
        lrun += __shfl_xor(lrun, 32);

        const float inv = 1.0f / fmaxf(lrun, 1e-30f);
        const size_t base = ((size_t)b * 2048 + query) * 1024 + hd * 64 + quad * 4;
#pragma unroll
        for (int n = 0; n < 4; n++) {
            bf16x4 ob;
#pragma unroll
            for (int r = 0; r < 4; r++) ob[r] = (bf16_t)(o[n][r] * inv);
            *(bf16x4*)&ctx[base + n * 16] = ob;
        }
    }
#undef ASTAGE
}

// ---------------------------------------------------------------------------
// Launcher. Inputs fp32, output fp32.
// ws bytes: [0,8M) hs_b -> (after gemm1) ctx overlay | [8M,14M) wqkv_b |
//           [14M,16M) wo_b | [16M,24M) q | [24M,32M) k | [32M,40M) v.
// ---------------------------------------------------------------------------
extern "C" void kernel_launch(void* const* d_in, const int* in_sizes, int n_in,
                              void* d_out, int out_size, void* d_ws, size_t ws_size,
                              hipStream_t stream) {
    const float* hs = (const float*)d_in[0];
    const float* cosb = (const float*)d_in[1];
    const float* sinb = (const float*)d_in[2];
    const float* wqkv = (const float*)d_in[3];
    const float* wo = (const float*)d_in[4];
    float* out = (float*)d_out;

    char* ws = (char*)d_ws;
    bf16_t* hs_b = (bf16_t*)(ws);
    bf16_t* wqkv_b = hs_b + 4194304;
    bf16_t* wo_b = hs_b + 7340032;
    bf16_t* q_ws = (bf16_t*)(ws + (size_t)(16u << 20));
    bf16_t* k_ws = (bf16_t*)(ws + (size_t)(24u << 20));
    bf16_t* v_ws = (bf16_t*)(ws + (size_t)(32u << 20));
    bf16_t* ctx = (bf16_t*)(ws);  // overlays hs_b (dead after gemm1)

    const dim3 blk(256);

    // 0) fp32 -> bf16 convert (hs | wqkv | wo packed)
    convert_kernel<<<dim3(4096), blk, 0, stream>>>(hs, wqkv, wo, hs_b);

    // 1) QKV projection + fused RoPE + scatter: M=4096, N=3072, K=1024
    gemm_bt<1, 3072, 128><<<dim3(24, 32), blk, 0, stream>>>(
        hs_b, wqkv_b, nullptr, q_ws, k_ws, v_ws, cosb, sinb);

    // 2) Flash attention (paired tiles, LDS-shared K/V, triple-buffered
    //    counted-vmcnt pipeline) -> ctx (bf16)
    attn_kernel<<<dim3(512), blk, 0, stream>>>(q_ws, k_ws, v_ws, ctx);

    // 3) Output projection: M=4096, N=1024, K=1024 (BM=64 -> 512 blocks)
    gemm_bt<0, 1024, 64><<<dim3(8, 64), blk, 0, stream>>>(
        ctx, wo_b, out, nullptr, nullptr, nullptr, nullptr, nullptr);
}

// Round 11
// 172.714 us; speedup vs baseline: 1.1155x; 1.0079x over previous
//
#include <hip/hip_runtime.h>

typedef __bf16 bf16_t;
typedef __bf16 bf16x4 __attribute__((ext_vector_type(4)));
typedef __bf16 bf16x8 __attribute__((ext_vector_type(8)));
typedef float f32x4 __attribute__((ext_vector_type(4)));
typedef unsigned int u32x2 __attribute__((ext_vector_type(2)));
typedef unsigned long long u64;

#define MFMA16(a, b, c) __builtin_amdgcn_mfma_f32_16x16x32_bf16((a), (b), (c), 0, 0, 0)

#define LDG2LDS16(g, l)                                                        \
    __builtin_amdgcn_global_load_lds(                                          \
        (const __attribute__((address_space(1))) void*)(g),                    \
        (__attribute__((address_space(3))) void*)(l), 16, 0, 0)

#if __has_builtin(__builtin_amdgcn_exp2f)
#define EXP2(x) __builtin_amdgcn_exp2f(x)
#else
#define EXP2(x) exp2f(x)
#endif

// load 8 consecutive fp32 as bf16x8
__device__ inline bf16x8 load8(const float* p) {
    const f32x4 a = *(const f32x4*)p;
    const f32x4 b = *(const f32x4*)(p + 4);
    bf16x8 r;
#pragma unroll
    for (int i = 0; i < 4; i++) { r[i] = (bf16_t)a[i]; r[4 + i] = (bf16_t)b[i]; }
    return r;
}

__device__ inline u32x2 as2(bf16x4 v) {
    u32x2 r;
    __builtin_memcpy(&r, &v, 8);
    return r;
}

// 8-byte cross-lane shuffle of a packed bf16x4 (fallback path)
__device__ inline bf16x4 shfl4(bf16x4 v, int src) {
    u64 x;
    __builtin_memcpy(&x, &v, 8);
    x = __shfl(x, src, 64);
    bf16x4 r;
    __builtin_memcpy(&r, &x, 8);
    return r;
}

// P C-layout (two bf16x4 regs covering 32 keys) -> PV B-fragment, via 6
// permlane swaps (verified algebra, rounds 0-10), ds_bpermute fallback.
__device__ inline bf16x8 p2pf(bf16x4 pb0, bf16x4 pb1, int quad, int lr) {
    bf16x8 pf;
#if __has_builtin(__builtin_amdgcn_permlane16_swap) && \
    __has_builtin(__builtin_amdgcn_permlane32_swap)
    const u32x2 P0 = as2(pb0);
    const u32x2 P1 = as2(pb1);
    const u32x2 s1a = __builtin_amdgcn_permlane16_swap(P0[0], P0[1], false, false);
    const u32x2 s1b = __builtin_amdgcn_permlane16_swap(P1[0], P1[1], false, false);
    const u32x2 s2a = __builtin_amdgcn_permlane32_swap(s1a[0], s1b[0], false, false);
    const u32x2 s2b = __builtin_amdgcn_permlane32_swap(s1a[1], s1b[1], false, false);
    const u32x2 s3a = __builtin_amdgcn_permlane16_swap(s2a[0], s2a[1], false, false);
    const u32x2 s3b = __builtin_amdgcn_permlane16_swap(s2b[0], s2b[1], false, false);
    const unsigned pfd[4] = {s3a[0], s3a[1], s3b[0], s3b[1]};
    __builtin_memcpy(&pf, pfd, 16);
#else
    const int srcLow = ((quad & 1) << 5) + lr;
    const int srcHigh = srcLow + 16;
    const bool loSel = (quad < 2);
    const bf16x4 a0 = shfl4(pb0, srcLow);
    const bf16x4 a1 = shfl4(pb1, srcLow);
    const bf16x4 b0 = shfl4(pb0, srcHigh);
    const bf16x4 b1 = shfl4(pb1, srcHigh);
    const bf16x4 lo = loSel ? a0 : a1;
    const bf16x4 hi = loSel ? b0 : b1;
#pragma unroll
    for (int r = 0; r < 4; r++) { pf[r] = lo[r]; pf[4 + r] = hi[r]; }
#endif
    return pf;
}

// ---------------------------------------------------------------------------
// fp32 -> bf16 convert: hs (4194304 el) | wqkv (3145728 el) | wo (1048576 el)
// ---------------------------------------------------------------------------
__global__ __launch_bounds__(256) void convert_kernel(const float* __restrict__ hs,
                                                      const float* __restrict__ wqkv,
                                                      const float* __restrict__ wo,
                                                      bf16_t* __restrict__ outb) {
    const size_t c = ((size_t)blockIdx.x * 256 + threadIdx.x) * 8;
    const float* src;
    size_t off;
    if (c < 4194304) { src = hs; off = c; }
    else if (c < 7340032) { src = wqkv; off = c - 4194304; }
    else { src = wo; off = c - 7340032; }
    *(bf16x8*)(outb + c) = load8(src + off);
}

// ---------------------------------------------------------------------------
// K/V swizzled layouts (MFMA-fragment order -> attn loads are base+lane*16):
//   k_sw: ((bh*128 + t>>4)*2 + (d>>5))*512 + ((t&15)+16*((d&31)>>3))*8 + (d&7)
//   v_sw: ((bh*64 + t>>5)*4 + (d>>4))*512 + ((d&15)+16*((t&31)>>3))*8 + (t&7)
// For a fixed 64-key tile kb, each of K/V occupies a CONTIGUOUS 4096-el (8 KB)
// region at base + kb*4096 -> a 128-key PAIR is a contiguous 8192-el region.
// ---------------------------------------------------------------------------

// ---------------------------------------------------------------------------
// GEMM (m97 structure, BK=32 — best measured 48.3us) + T2 XOR swizzle
// (conflicts measured 0).
// ---------------------------------------------------------------------------
template <int MODE, int NDIM, int BM>
__global__ __launch_bounds__(256) void gemm_bt(const bf16_t* __restrict__ A,
                                               const bf16_t* __restrict__ B,
                                               float* __restrict__ outp,
                                               bf16_t* __restrict__ q_ws,
                                               bf16_t* __restrict__ k_ws,
                                               bf16_t* __restrict__ v_ws,
                                               const float* __restrict__ cosb,
                                               const float* __restrict__ sinb) {
    constexpr int K = 1024;
    constexpr int IM = BM / 32;
    __shared__ __align__(16) bf16_t As[BM * 32];
    __shared__ __align__(16) bf16_t Bs[128 * 32];

    const int tid = threadIdx.x;
    const int w = tid >> 6;
    const int lane = tid & 63;
    const int lr = lane & 15;
    const int quad = lane >> 4;
    const int m0 = blockIdx.y * BM;
    const int n0 = blockIdx.x * 128;
    const int wm = (w & 1) * (BM / 2);
    const int wn = (w >> 1) * 64;

    const int srow = tid >> 2;
    // source slot pre-swizzled: slot ^ f(row), f(row) = (row>>1)&3
    const int skk = (((tid & 3) ^ ((tid >> 3) & 3)) * 8);
    const bf16_t* gA0 = A + (size_t)(m0 + srow) * K + skk;
    const bf16_t* gA1 = gA0 + (size_t)64 * K;
    const bf16_t* gB0 = B + (size_t)(n0 + srow) * K + skk;
    const bf16_t* gB1 = gB0 + (size_t)64 * K;
    bf16_t* lA0 = As + w * 512;
    bf16_t* lA1 = As + 2048 + w * 512;
    bf16_t* lB0 = Bs + w * 512;
    bf16_t* lB1 = Bs + 2048 + w * 512;

    // fragment-read slot: quad ^ f(row); row low bits = lr -> f = (lr>>1)&3
    const int qsw = (quad ^ ((lr >> 1) & 3)) * 8;

    f32x4 acc[IM][4] = {};

    for (int k0 = 0; k0 < K; k0 += 32) {
        LDG2LDS16(gA0 + k0, lA0);
        if constexpr (BM == 128) LDG2LDS16(gA1 + k0, lA1);
        LDG2LDS16(gB0 + k0, lB0);
        LDG2LDS16(gB1 + k0, lB1);
        __syncthreads();

        bf16x8 af[IM], bfm[4];
#pragma unroll
        for (int im = 0; im < IM; im++)
            af[im] = *(const bf16x8*)&As[(wm + im * 16 + lr) * 32 + qsw];
#pragma unroll
        for (int in = 0; in < 4; in++)
            bfm[in] = *(const bf16x8*)&Bs[(wn + in * 16 + lr) * 32 + qsw];
#pragma unroll
        for (int im = 0; im < IM; im++)
#pragma unroll
            for (int in = 0; in < 4; in++)
                acc[im][in] = MFMA16(af[im], bfm[in], acc[im][in]);
        __syncthreads();
    }

    if constexpr (MODE == 0) {
#pragma unroll
        for (int im = 0; im < IM; im++)
#pragma unroll
            for (int in = 0; in < 4; in++)
#pragma unroll
                for (int r = 0; r < 4; r++) {
                    const int m = m0 + wm + im * 16 + quad * 4 + r;
                    const int n = n0 + wn + in * 16 + lr;
                    outp[(size_t)m * NDIM + n] = acc[im][in][r];
                }
    } else {
        const int j = (n0 + wn) >> 6;
        if (j < 32) {
            const bool isq = (j < 16);
            const float qs = 0.125f * 1.44269504089f;
#pragma unroll
            for (int im = 0; im < IM; im++) {
#pragma unroll
                for (int r = 0; r < 4; r++) {
                    const int m = m0 + wm + im * 16 + quad * 4 + r;
                    const int b = m >> 11;
                    const int t = m & 2047;
#pragma unroll
                    for (int in = 0; in < 2; in++) {
                        const int d = in * 16 + lr;
                        const float x1 = acc[im][in][r];
                        const float x2 = acc[im][in + 2][r];
                        const float c = cosb[t * 64 + d];
                        const float s = sinb[t * 64 + d];
                        float y1 = x1 * c - x2 * s;
                        float y2 = x2 * c + x1 * s;
                        if (isq) {
                            y1 *= qs; y2 *= qs;
                            const size_t base =
                                ((size_t)(b * 16 + j) * 2048 + t) * 64 + d;
                            q_ws[base] = (bf16_t)y1;
                            q_ws[base + 32] = (bf16_t)y2;
                        } else {
                            const int bh = b * 16 + (j - 16);
                            const size_t off =
                                ((size_t)(bh * 128 + (t >> 4)) * 2) * 512 +
                                ((t & 15) + (d >> 3) * 16) * 8 + (d & 7);
                            k_ws[off] = (bf16_t)y1;
                            k_ws[off + 512] = (bf16_t)y2;
                        }
                    }
                }
            }
        } else {
#pragma unroll
            for (int im = 0; im < IM; im++)
#pragma unroll
                for (int in = 0; in < 4; in++)
#pragma unroll
                    for (int r = 0; r < 4; r++) {
                        const int m = m0 + wm + im * 16 + quad * 4 + r;
                        const int b = m >> 11;
                        const int t = m & 2047;
                        const int d = in * 16 + lr;
                        const int bh = b * 16 + (j - 32);
                        const size_t off =
                            ((size_t)(bh * 64 + (t >> 5)) * 4 + (d >> 4)) * 512 +
                            ((d & 15) + ((t & 31) >> 3) * 16) * 8 + (t & 7);
                        v_ws[off] = (bf16_t)acc[im][in][r];
                    }
        }
    }
}

// ---------------------------------------------------------------------------
// Flash attention (round 11): round-7 structure (paired halves, 512 WGs,
// bh=blockIdx&31 -> 4 bh streams/XCD L2-resident, LDS-shared K/V, identical
// sync shape) with KVBLK doubled to 128: each iteration stages a 128-key
// K+V PAIR (16 KB each, double-buffered, 64 KB LDS -> still 2 WGs/CU since
// the grid is the binding occupancy limit) and computes both 64-key subtiles
// before the single lgkmcnt(0)+vmcnt(0)+s_barrier. Barrier rendezvous per WG:
// 35 -> ~19 (r8 profile: attn is ~52% VALU, 12% MFMA, rest per-iteration
// stall; r10 ruled out the vmcnt drain -> the remaining candidate is the
// rendezvous count itself; r6's analogous GEMM change regressed via
// occupancy loss, which does NOT occur here).
// Odd-tile tails: wave-uniform guards; last-pair staging stages only valid
// tiles (no reads past the v_ws region). Math/masking/permlane/output
// byte-identical to round 7.
// ---------------------------------------------------------------------------
__global__ __launch_bounds__(256) void attn_kernel(const bf16_t* __restrict__ q_ws,
                                                   const bf16_t* __restrict__ k_ws,
                                                   const bf16_t* __restrict__ v_ws,
                                                   bf16_t* __restrict__ ctx) {
    __shared__ __align__(16) bf16_t Ks[2][8192];  // 2 x 16 KB (128-key pair)
    __shared__ __align__(16) bf16_t Vs[2][8192];  // 2 x 16 KB

    const int tid = threadIdx.x;
    const int w = tid >> 6;
    const int lane = tid & 63;
    const int lr = lane & 15;
    const int quad = lane >> 4;
    const int bh = blockIdx.x & 31;
    const int pr = blockIdx.x >> 5;  // 0..15
    const int b = bh >> 4;
    const int hd = bh & 15;

    const bf16_t* kws = k_ws + (size_t)bh * 131072;
    const bf16_t* vws = v_ws + (size_t)bh * 131072;
    const int soff = w * 512 + lane * 8;  // per-lane element offset in a sweep
    const int lo8 = lane * 8;

    // stage a 128-key pair p (tiles 2p, 2p+1): 4(+4 if full) LDG sweeps each
#define ASTAGE2(p, buf, full)                                                  \
    {                                                                          \
        LDG2LDS16(kws + (size_t)(p) * 8192 + soff, &Ks[buf][w * 512]);         \
        LDG2LDS16(kws + (size_t)(p) * 8192 + 2048 + soff,                      \
                  &Ks[buf][2048 + w * 512]);                                   \
        LDG2LDS16(vws + (size_t)(p) * 8192 + soff, &Vs[buf][w * 512]);         \
        LDG2LDS16(vws + (size_t)(p) * 8192 + 2048 + soff,                      \
                  &Vs[buf][2048 + w * 512]);                                   \
        if (full) {                                                            \
            LDG2LDS16(kws + (size_t)(p) * 8192 + 4096 + soff,                  \
                      &Ks[buf][4096 + w * 512]);                               \
            LDG2LDS16(kws + (size_t)(p) * 8192 + 6144 + soff,                  \
                      &Ks[buf][6144 + w * 512]);                               \
            LDG2LDS16(vws + (size_t)(p) * 8192 + 4096 + soff,                  \
                      &Vs[buf][4096 + w * 512]);                               \
            LDG2LDS16(vws + (size_t)(p) * 8192 + 6144 + soff,                  \
                      &Vs[buf][6144 + w * 512]);                               \
        }                                                                      \
    }

// one 64-key subtile s (0/1) of pair in buf; key-tile index kb
#define SUBTILE(buf, s, kb)                                                    \
    {                                                                          \
        f32x4 sc[4];                                                           \
        _Pragma("unroll") for (int n = 0; n < 4; n++) {                        \
            const bf16x8 k0 =                                                  \
                *(const bf16x8*)&Ks[buf][(s) * 4096 + (2 * n) * 512 + lo8];    \
            const bf16x8 k1 =                                                  \
                *(const bf16x8*)&Ks[buf][(s) * 4096 + (2 * n + 1) * 512 + lo8];\
            const f32x4 z = {};                                                \
            sc[n] = MFMA16(k0, qlo, z);                                        \
            sc[n] = MFMA16(k1, qhi, sc[n]);                                    \
        }                                                                      \
        const int u0 = (kb) * 64;                                              \
        if ((kb) == qt) {                                                      \
            _Pragma("unroll") for (int n = 0; n < 4; n++)                      \
                _Pragma("unroll") for (int r = 0; r < 4; r++)                  \
                    if (u0 + n * 16 + quad * 4 + r > query) sc[n][r] = -1e9f;  \
        }                                                                      \
        f32x4 pp[4];                                                           \
        _Pragma("unroll") for (int n = 0; n < 4; n++)                          \
            _Pragma("unroll") for (int r = 0; r < 4; r++)                      \
                pp[n][r] = EXP2(sc[n][r]);                                     \
        lrun += ((pp[0][0] + pp[0][1]) + (pp[0][2] + pp[0][3])) +              \
                ((pp[1][0] + pp[1][1]) + (pp[1][2] + pp[1][3])) +              \
                ((pp[2][0] + pp[2][1]) + (pp[2][2] + pp[2][3])) +              \
                ((pp[3][0] + pp[3][1]) + (pp[3][2] + pp[3][3]));               \
        bf16x4 pb[4];                                                          \
        _Pragma("unroll") for (int n = 0; n < 4; n++)                          \
            _Pragma("unroll") for (int r = 0; r < 4; r++)                      \
                pb[n][r] = (bf16_t)pp[n][r];                                   \
        _Pragma("unroll") for (int hh = 0; hh < 2; hh++) {                     \
            const bf16x8 pf = p2pf(pb[2 * hh], pb[2 * hh + 1], quad, lr);      \
            _Pragma("unroll") for (int n = 0; n < 4; n++) {                    \
                const bf16x8 vvf = *(const bf16x8*)                            \
                    &Vs[buf][(s) * 4096 + (hh * 4 + n) * 512 + lo8];           \
                o[n] = MFMA16(vvf, pf, o[n]);                                  \
            }                                                                  \
        }                                                                      \
    }

#pragma unroll
    for (int half = 0; half < 2; half++) {
        const int qt = half ? (31 - pr) : pr;
        const int nt = qt + 1;                // 64-key tiles
        const int npairs = (nt + 1) >> 1;     // 128-key pairs
        const int trow = qt * 64 + w * 16;
        const int query = trow + lr;

        const bf16_t* qb = q_ws + ((size_t)bh * 2048 + trow + lr) * 64 + quad * 8;
        const bf16x8 qlo = *(const bf16x8*)qb;
        const bf16x8 qhi = *(const bf16x8*)(qb + 32);

        f32x4 o[4] = {};
        float lrun = 0.0f;

        // prologue: stage pair 0 (second subtile only if it exists)
        ASTAGE2(0, 0, nt > 1);
        asm volatile("s_waitcnt vmcnt(0)" ::: "memory");
        __builtin_amdgcn_s_barrier();
        asm volatile("" ::: "memory");

        for (int i = 0; i < npairs; i++) {
            const int buf = i & 1;
            if (i + 1 < npairs)
                ASTAGE2(i + 1, buf ^ 1, (2 * (i + 1) + 1) < nt);

            SUBTILE(buf, 0, 2 * i);
            if (2 * i + 1 < nt) SUBTILE(buf, 1, 2 * i + 1);

            // all LDS reads of buf done; this wave's stage loads landed
            asm volatile("s_waitcnt lgkmcnt(0) vmcnt(0)" ::: "memory");
            __builtin_amdgcn_s_barrier();
            asm volatile("" ::: "memory");
        }

        lrun += __shfl_xor(lrun, 16);
        lrun += __shfl_xor(lrun, 32);

        const float inv = 1.0f / fmaxf(lrun, 1e-30f);
        const size_t base = ((size_t)b * 2048 + query) * 1024 + hd * 64 + quad * 4;
#pragma unroll
        for (int n = 0; n < 4; n++) {
            bf16x4 ob;
#pragma unroll
            for (int r = 0; r < 4; r++) ob[r] = (bf16_t)(o[n][r] * inv);
            *(bf16x4*)&ctx[base + n * 16] = ob;
        }
    }
#undef ASTAGE2
#undef SUBTILE
}

// ---------------------------------------------------------------------------
// Launcher. Inputs fp32, output fp32.
// ws bytes: [0,8M) hs_b -> (after gemm1) ctx overlay | [8M,14M) wqkv_b |
//           [14M,16M) wo_b | [16M,24M) q | [24M,32M) k | [32M,40M) v.
// ---------------------------------------------------------------------------
extern "C" void kernel_launch(void* const* d_in, const int* in_sizes, int n_in,
                              void* d_out, int out_size, void* d_ws, size_t ws_size,
                              hipStream_t stream) {
    const float* hs = (const float*)d_in[0];
    const float* cosb = (const float*)d_in[1];
    const float* sinb = (const float*)d_in[2];
    const float* wqkv = (const float*)d_in[3];
    const float* wo = (const float*)d_in[4];
    float* out = (float*)d_out;

    char* ws = (char*)d_ws;
    bf16_t* hs_b = (bf16_t*)(ws);
    bf16_t* wqkv_b = hs_b + 4194304;
    bf16_t* wo_b = hs_b + 7340032;
    bf16_t* q_ws = (bf16_t*)(ws + (size_t)(16u << 20));
    bf16_t* k_ws = (bf16_t*)(ws + (size_t)(24u << 20));
    bf16_t* v_ws = (bf16_t*)(ws + (size_t)(32u << 20));
    bf16_t* ctx = (bf16_t*)(ws);  // overlays hs_b (dead after gemm1)

    const dim3 blk(256);

    // 0) fp32 -> bf16 convert (hs | wqkv | wo packed)
    convert_kernel<<<dim3(4096), blk, 0, stream>>>(hs, wqkv, wo, hs_b);

    // 1) QKV projection + fused RoPE + scatter: M=4096, N=3072, K=1024
    gemm_bt<1, 3072, 128><<<dim3(24, 32), blk, 0, stream>>>(
        hs_b, wqkv_b, nullptr, q_ws, k_ws, v_ws, cosb, sinb);

    // 2) Flash attention (paired halves, 128-key pairs, LDS-shared K/V)
    attn_kernel<<<dim3(512), blk, 0, stream>>>(q_ws, k_ws, v_ws, ctx);

    // 3) Output projection: M=4096, N=1024, K=1024 (BM=64 -> 512 blocks)
    gemm_bt<0, 1024, 64><<<dim3(8, 64), blk, 0, stream>>>(
        ctx, wo_b, out, nullptr, nullptr, nullptr, nullptr, nullptr);
}

// Round 12
// 171.200 us; speedup vs baseline: 1.1253x; 1.0088x over previous
//
#include <hip/hip_runtime.h>

typedef __bf16 bf16_t;
typedef __bf16 bf16x4 __attribute__((ext_vector_type(4)));
typedef __bf16 bf16x8 __attribute__((ext_vector_type(8)));
typedef float f32x4 __attribute__((ext_vector_type(4)));
typedef unsigned int u32x2 __attribute__((ext_vector_type(2)));
typedef unsigned long long u64;

#define MFMA16(a, b, c) __builtin_amdgcn_mfma_f32_16x16x32_bf16((a), (b), (c), 0, 0, 0)

#define LDG2LDS16(g, l)                                                        \
    __builtin_amdgcn_global_load_lds(                                          \
        (const __attribute__((address_space(1))) void*)(g),                    \
        (__attribute__((address_space(3))) void*)(l), 16, 0, 0)

#if __has_builtin(__builtin_amdgcn_exp2f)
#define EXP2(x) __builtin_amdgcn_exp2f(x)
#else
#define EXP2(x) exp2f(x)
#endif

// load 8 consecutive fp32 as bf16x8
__device__ inline bf16x8 load8(const float* p) {
    const f32x4 a = *(const f32x4*)p;
    const f32x4 b = *(const f32x4*)(p + 4);
    bf16x8 r;
#pragma unroll
    for (int i = 0; i < 4; i++) { r[i] = (bf16_t)a[i]; r[4 + i] = (bf16_t)b[i]; }
    return r;
}

__device__ inline u32x2 as2(bf16x4 v) {
    u32x2 r;
    __builtin_memcpy(&r, &v, 8);
    return r;
}

// 8-byte cross-lane shuffle of a packed bf16x4 (fallback path)
__device__ inline bf16x4 shfl4(bf16x4 v, int src) {
    u64 x;
    __builtin_memcpy(&x, &v, 8);
    x = __shfl(x, src, 64);
    bf16x4 r;
    __builtin_memcpy(&r, &x, 8);
    return r;
}

// P C-layout (two bf16x4 regs covering 32 keys) -> PV B-fragment, via 6
// permlane swaps (verified algebra, rounds 0-11), ds_bpermute fallback.
__device__ inline bf16x8 p2pf(bf16x4 pb0, bf16x4 pb1, int quad, int lr) {
    bf16x8 pf;
#if __has_builtin(__builtin_amdgcn_permlane16_swap) && \
    __has_builtin(__builtin_amdgcn_permlane32_swap)
    const u32x2 P0 = as2(pb0);
    const u32x2 P1 = as2(pb1);
    const u32x2 s1a = __builtin_amdgcn_permlane16_swap(P0[0], P0[1], false, false);
    const u32x2 s1b = __builtin_amdgcn_permlane16_swap(P1[0], P1[1], false, false);
    const u32x2 s2a = __builtin_amdgcn_permlane32_swap(s1a[0], s1b[0], false, false);
    const u32x2 s2b = __builtin_amdgcn_permlane32_swap(s1a[1], s1b[1], false, false);
    const u32x2 s3a = __builtin_amdgcn_permlane16_swap(s2a[0], s2a[1], false, false);
    const u32x2 s3b = __builtin_amdgcn_permlane16_swap(s2b[0], s2b[1], false, false);
    const unsigned pfd[4] = {s3a[0], s3a[1], s3b[0], s3b[1]};
    __builtin_memcpy(&pf, pfd, 16);
#else
    const int srcLow = ((quad & 1) << 5) + lr;
    const int srcHigh = srcLow + 16;
    const bool loSel = (quad < 2);
    const bf16x4 a0 = shfl4(pb0, srcLow);
    const bf16x4 a1 = shfl4(pb1, srcLow);
    const bf16x4 b0 = shfl4(pb0, srcHigh);
    const bf16x4 b1 = shfl4(pb1, srcHigh);
    const bf16x4 lo = loSel ? a0 : a1;
    const bf16x4 hi = loSel ? b0 : b1;
#pragma unroll
    for (int r = 0; r < 4; r++) { pf[r] = lo[r]; pf[4 + r] = hi[r]; }
#endif
    return pf;
}

// ---------------------------------------------------------------------------
// fp32 -> bf16 convert: hs (4194304 el) | wqkv (3145728 el) | wo (1048576 el)
// ---------------------------------------------------------------------------
__global__ __launch_bounds__(256) void convert_kernel(const float* __restrict__ hs,
                                                      const float* __restrict__ wqkv,
                                                      const float* __restrict__ wo,
                                                      bf16_t* __restrict__ outb) {
    const size_t c = ((size_t)blockIdx.x * 256 + threadIdx.x) * 8;
    const float* src;
    size_t off;
    if (c < 4194304) { src = hs; off = c; }
    else if (c < 7340032) { src = wqkv; off = c - 4194304; }
    else { src = wo; off = c - 7340032; }
    *(bf16x8*)(outb + c) = load8(src + off);
}

// ---------------------------------------------------------------------------
// K/V swizzled layouts (MFMA-fragment order -> attn loads are base+lane*16):
//   k_sw: ((bh*128 + t>>4)*2 + (d>>5))*512 + ((t&15)+16*((d&31)>>3))*8 + (d&7)
//   v_sw: ((bh*64 + t>>5)*4 + (d>>4))*512 + ((d&15)+16*((t&31)>>3))*8 + (t&7)
// For a fixed 64-key tile kb, each of K/V occupies a CONTIGUOUS 4096-el (8 KB)
// region at base + kb*4096 -> a 128-key PAIR is a contiguous 8192-el region.
// ---------------------------------------------------------------------------

// ---------------------------------------------------------------------------
// GEMM (m97 structure, BK=32 — best measured 48.3us) + T2 XOR swizzle
// (conflicts measured 0).
// ---------------------------------------------------------------------------
template <int MODE, int NDIM, int BM>
__global__ __launch_bounds__(256) void gemm_bt(const bf16_t* __restrict__ A,
                                               const bf16_t* __restrict__ B,
                                               float* __restrict__ outp,
                                               bf16_t* __restrict__ q_ws,
                                               bf16_t* __restrict__ k_ws,
                                               bf16_t* __restrict__ v_ws,
                                               const float* __restrict__ cosb,
                                               const float* __restrict__ sinb) {
    constexpr int K = 1024;
    constexpr int IM = BM / 32;
    __shared__ __align__(16) bf16_t As[BM * 32];
    __shared__ __align__(16) bf16_t Bs[128 * 32];

    const int tid = threadIdx.x;
    const int w = tid >> 6;
    const int lane = tid & 63;
    const int lr = lane & 15;
    const int quad = lane >> 4;
    const int m0 = blockIdx.y * BM;
    const int n0 = blockIdx.x * 128;
    const int wm = (w & 1) * (BM / 2);
    const int wn = (w >> 1) * 64;

    const int srow = tid >> 2;
    // source slot pre-swizzled: slot ^ f(row), f(row) = (row>>1)&3
    const int skk = (((tid & 3) ^ ((tid >> 3) & 3)) * 8);
    const bf16_t* gA0 = A + (size_t)(m0 + srow) * K + skk;
    const bf16_t* gA1 = gA0 + (size_t)64 * K;
    const bf16_t* gB0 = B + (size_t)(n0 + srow) * K + skk;
    const bf16_t* gB1 = gB0 + (size_t)64 * K;
    bf16_t* lA0 = As + w * 512;
    bf16_t* lA1 = As + 2048 + w * 512;
    bf16_t* lB0 = Bs + w * 512;
    bf16_t* lB1 = Bs + 2048 + w * 512;

    // fragment-read slot: quad ^ f(row); row low bits = lr -> f = (lr>>1)&3
    const int qsw = (quad ^ ((lr >> 1) & 3)) * 8;

    f32x4 acc[IM][4] = {};

    for (int k0 = 0; k0 < K; k0 += 32) {
        LDG2LDS16(gA0 + k0, lA0);
        if constexpr (BM == 128) LDG2LDS16(gA1 + k0, lA1);
        LDG2LDS16(gB0 + k0, lB0);
        LDG2LDS16(gB1 + k0, lB1);
        __syncthreads();

        bf16x8 af[IM], bfm[4];
#pragma unroll
        for (int im = 0; im < IM; im++)
            af[im] = *(const bf16x8*)&As[(wm + im * 16 + lr) * 32 + qsw];
#pragma unroll
        for (int in = 0; in < 4; in++)
            bfm[in] = *(const bf16x8*)&Bs[(wn + in * 16 + lr) * 32 + qsw];
#pragma unroll
        for (int im = 0; im < IM; im++)
#pragma unroll
            for (int in = 0; in < 4; in++)
                acc[im][in] = MFMA16(af[im], bfm[in], acc[im][in]);
        __syncthreads();
    }

    if constexpr (MODE == 0) {
#pragma unroll
        for (int im = 0; im < IM; im++)
#pragma unroll
            for (int in = 0; in < 4; in++)
#pragma unroll
                for (int r = 0; r < 4; r++) {
                    const int m = m0 + wm + im * 16 + quad * 4 + r;
                    const int n = n0 + wn + in * 16 + lr;
                    outp[(size_t)m * NDIM + n] = acc[im][in][r];
                }
    } else {
        const int j = (n0 + wn) >> 6;
        if (j < 32) {
            const bool isq = (j < 16);
            const float qs = 0.125f * 1.44269504089f;
#pragma unroll
            for (int im = 0; im < IM; im++) {
#pragma unroll
                for (int r = 0; r < 4; r++) {
                    const int m = m0 + wm + im * 16 + quad * 4 + r;
                    const int b = m >> 11;
                    const int t = m & 2047;
#pragma unroll
                    for (int in = 0; in < 2; in++) {
                        const int d = in * 16 + lr;
                        const float x1 = acc[im][in][r];
                        const float x2 = acc[im][in + 2][r];
                        const float c = cosb[t * 64 + d];
                        const float s = sinb[t * 64 + d];
                        float y1 = x1 * c - x2 * s;
                        float y2 = x2 * c + x1 * s;
                        if (isq) {
                            y1 *= qs; y2 *= qs;
                            const size_t base =
                                ((size_t)(b * 16 + j) * 2048 + t) * 64 + d;
                            q_ws[base] = (bf16_t)y1;
                            q_ws[base + 32] = (bf16_t)y2;
                        } else {
                            const int bh = b * 16 + (j - 16);
                            const size_t off =
                                ((size_t)(bh * 128 + (t >> 4)) * 2) * 512 +
                                ((t & 15) + (d >> 3) * 16) * 8 + (d & 7);
                            k_ws[off] = (bf16_t)y1;
                            k_ws[off + 512] = (bf16_t)y2;
                        }
                    }
                }
            }
        } else {
#pragma unroll
            for (int im = 0; im < IM; im++)
#pragma unroll
                for (int in = 0; in < 4; in++)
#pragma unroll
                    for (int r = 0; r < 4; r++) {
                        const int m = m0 + wm + im * 16 + quad * 4 + r;
                        const int b = m >> 11;
                        const int t = m & 2047;
                        const int d = in * 16 + lr;
                        const int bh = b * 16 + (j - 32);
                        const size_t off =
                            ((size_t)(bh * 64 + (t >> 5)) * 4 + (d >> 4)) * 512 +
                            ((d & 15) + ((t & 31) >> 3) * 16) * 8 + (t & 7);
                        v_ws[off] = (bf16_t)acc[im][in][r];
                    }
        }
    }
}

// ---------------------------------------------------------------------------
// Flash attention (round 12): round-11 structure (paired halves, 512 WGs,
// bh=blockIdx&31 L2 residency, 128-key pairs, LDS-shared K/V, verified sync)
// with the softmax row-sum moved OFF the VALU: an all-ones A-fragment MFMA
// per 32-key half accumulates sum_k P[k][q] into lacc (every output row equals
// the denominator; lane's col = its query), replacing the 15-op f32 add tree
// AND the end-of-tile shfl_xor quad-reduce. Matrix pipe was 12% busy -> the 2
// extra MFMAs/subtile are hidden; VALU chain (measured 52% busy, the attn
// bottleneck after r9/r10/r11 ruled out occupancy/drain/rendezvous) shrinks
// ~22%. Denominator now sums the same bf16-rounded P used by the PV numerator.
// ---------------------------------------------------------------------------
__global__ __launch_bounds__(256) void attn_kernel(const bf16_t* __restrict__ q_ws,
                                                   const bf16_t* __restrict__ k_ws,
                                                   const bf16_t* __restrict__ v_ws,
                                                   bf16_t* __restrict__ ctx) {
    __shared__ __align__(16) bf16_t Ks[2][8192];  // 2 x 16 KB (128-key pair)
    __shared__ __align__(16) bf16_t Vs[2][8192];  // 2 x 16 KB

    const int tid = threadIdx.x;
    const int w = tid >> 6;
    const int lane = tid & 63;
    const int lr = lane & 15;
    const int quad = lane >> 4;
    const int bh = blockIdx.x & 31;
    const int pr = blockIdx.x >> 5;  // 0..15
    const int b = bh >> 4;
    const int hd = bh & 15;

    const bf16_t* kws = k_ws + (size_t)bh * 131072;
    const bf16_t* vws = v_ws + (size_t)bh * 131072;
    const int soff = w * 512 + lane * 8;  // per-lane element offset in a sweep
    const int lo8 = lane * 8;

    bf16x8 ones8;
#pragma unroll
    for (int i = 0; i < 8; i++) ones8[i] = (bf16_t)1.0f;

    // stage a 128-key pair p (tiles 2p, 2p+1): 4(+4 if full) LDG sweeps each
#define ASTAGE2(p, buf, full)                                                  \
    {                                                                          \
        LDG2LDS16(kws + (size_t)(p) * 8192 + soff, &Ks[buf][w * 512]);         \
        LDG2LDS16(kws + (size_t)(p) * 8192 + 2048 + soff,                      \
                  &Ks[buf][2048 + w * 512]);                                   \
        LDG2LDS16(vws + (size_t)(p) * 8192 + soff, &Vs[buf][w * 512]);         \
        LDG2LDS16(vws + (size_t)(p) * 8192 + 2048 + soff,                      \
                  &Vs[buf][2048 + w * 512]);                                   \
        if (full) {                                                            \
            LDG2LDS16(kws + (size_t)(p) * 8192 + 4096 + soff,                  \
                      &Ks[buf][4096 + w * 512]);                               \
            LDG2LDS16(kws + (size_t)(p) * 8192 + 6144 + soff,                  \
                      &Ks[buf][6144 + w * 512]);                               \
            LDG2LDS16(vws + (size_t)(p) * 8192 + 4096 + soff,                  \
                      &Vs[buf][4096 + w * 512]);                               \
            LDG2LDS16(vws + (size_t)(p) * 8192 + 6144 + soff,                  \
                      &Vs[buf][6144 + w * 512]);                               \
        }                                                                      \
    }

// one 64-key subtile s (0/1) of pair in buf; key-tile index kb
#define SUBTILE(buf, s, kb)                                                    \
    {                                                                          \
        f32x4 sc[4];                                                           \
        _Pragma("unroll") for (int n = 0; n < 4; n++) {                        \
            const bf16x8 k0 =                                                  \
                *(const bf16x8*)&Ks[buf][(s) * 4096 + (2 * n) * 512 + lo8];    \
            const bf16x8 k1 =                                                  \
                *(const bf16x8*)&Ks[buf][(s) * 4096 + (2 * n + 1) * 512 + lo8];\
            const f32x4 z = {};                                                \
            sc[n] = MFMA16(k0, qlo, z);                                        \
            sc[n] = MFMA16(k1, qhi, sc[n]);                                    \
        }                                                                      \
        const int u0 = (kb) * 64;                                              \
        if ((kb) == qt) {                                                      \
            _Pragma("unroll") for (int n = 0; n < 4; n++)                      \
                _Pragma("unroll") for (int r = 0; r < 4; r++)                  \
                    if (u0 + n * 16 + quad * 4 + r > query) sc[n][r] = -1e9f;  \
        }                                                                      \
        bf16x4 pb[4];                                                          \
        _Pragma("unroll") for (int n = 0; n < 4; n++)                          \
            _Pragma("unroll") for (int r = 0; r < 4; r++)                      \
                pb[n][r] = (bf16_t)EXP2(sc[n][r]);                             \
        _Pragma("unroll") for (int hh = 0; hh < 2; hh++) {                     \
            const bf16x8 pf = p2pf(pb[2 * hh], pb[2 * hh + 1], quad, lr);      \
            lacc = MFMA16(ones8, pf, lacc);                                    \
            _Pragma("unroll") for (int n = 0; n < 4; n++) {                    \
                const bf16x8 vvf = *(const bf16x8*)                            \
                    &Vs[buf][(s) * 4096 + (hh * 4 + n) * 512 + lo8];           \
                o[n] = MFMA16(vvf, pf, o[n]);                                  \
            }                                                                  \
        }                                                                      \
    }

#pragma unroll
    for (int half = 0; half < 2; half++) {
        const int qt = half ? (31 - pr) : pr;
        const int nt = qt + 1;                // 64-key tiles
        const int npairs = (nt + 1) >> 1;     // 128-key pairs
        const int trow = qt * 64 + w * 16;
        const int query = trow + lr;

        const bf16_t* qb = q_ws + ((size_t)bh * 2048 + trow + lr) * 64 + quad * 8;
        const bf16x8 qlo = *(const bf16x8*)qb;
        const bf16x8 qhi = *(const bf16x8*)(qb + 32);

        f32x4 o[4] = {};
        f32x4 lacc = {};

        // prologue: stage pair 0 (second subtile only if it exists)
        ASTAGE2(0, 0, nt > 1);
        asm volatile("s_waitcnt vmcnt(0)" ::: "memory");
        __builtin_amdgcn_s_barrier();
        asm volatile("" ::: "memory");

        for (int i = 0; i < npairs; i++) {
            const int buf = i & 1;
            if (i + 1 < npairs)
                ASTAGE2(i + 1, buf ^ 1, (2 * (i + 1) + 1) < nt);

            SUBTILE(buf, 0, 2 * i);
            if (2 * i + 1 < nt) SUBTILE(buf, 1, 2 * i + 1);

            // all LDS reads of buf done; this wave's stage loads landed
            asm volatile("s_waitcnt lgkmcnt(0) vmcnt(0)" ::: "memory");
            __builtin_amdgcn_s_barrier();
            asm volatile("" ::: "memory");
        }

        // lacc rows are all equal to sum_k P[k][query] -> take reg 0.
        const float inv = 1.0f / fmaxf(lacc[0], 1e-30f);
        const size_t base = ((size_t)b * 2048 + query) * 1024 + hd * 64 + quad * 4;
#pragma unroll
        for (int n = 0; n < 4; n++) {
            bf16x4 ob;
#pragma unroll
            for (int r = 0; r < 4; r++) ob[r] = (bf16_t)(o[n][r] * inv);
            *(bf16x4*)&ctx[base + n * 16] = ob;
        }
    }
#undef ASTAGE2
#undef SUBTILE
}

// ---------------------------------------------------------------------------
// Launcher. Inputs fp32, output fp32.
// ws bytes: [0,8M) hs_b -> (after gemm1) ctx overlay | [8M,14M) wqkv_b |
//           [14M,16M) wo_b | [16M,24M) q | [24M,32M) k | [32M,40M) v.
// ---------------------------------------------------------------------------
extern "C" void kernel_launch(void* const* d_in, const int* in_sizes, int n_in,
                              void* d_out, int out_size, void* d_ws, size_t ws_size,
                              hipStream_t stream) {
    const float* hs = (const float*)d_in[0];
    const float* cosb = (const float*)d_in[1];
    const float* sinb = (const float*)d_in[2];
    const float* wqkv = (const float*)d_in[3];
    const float* wo = (const float*)d_in[4];
    float* out = (float*)d_out;

    char* ws = (char*)d_ws;
    bf16_t* hs_b = (bf16_t*)(ws);
    bf16_t* wqkv_b = hs_b + 4194304;
    bf16_t* wo_b = hs_b + 7340032;
    bf16_t* q_ws = (bf16_t*)(ws + (size_t)(16u << 20));
    bf16_t* k_ws = (bf16_t*)(ws + (size_t)(24u << 20));
    bf16_t* v_ws = (bf16_t*)(ws + (size_t)(32u << 20));
    bf16_t* ctx = (bf16_t*)(ws);  // overlays hs_b (dead after gemm1)

    const dim3 blk(256);

    // 0) fp32 -> bf16 convert (hs | wqkv | wo packed)
    convert_kernel<<<dim3(4096), blk, 0, stream>>>(hs, wqkv, wo, hs_b);

    // 1) QKV projection + fused RoPE + scatter: M=4096, N=3072, K=1024
    gemm_bt<1, 3072, 128><<<dim3(24, 32), blk, 0, stream>>>(
        hs_b, wqkv_b, nullptr, q_ws, k_ws, v_ws, cosb, sinb);

    // 2) Flash attention (paired halves, 128-key pairs, ones-MFMA row-sum)
    attn_kernel<<<dim3(512), blk, 0, stream>>>(q_ws, k_ws, v_ws, ctx);

    // 3) Output projection: M=4096, N=1024, K=1024 (BM=64 -> 512 blocks)
    gemm_bt<0, 1024, 64><<<dim3(8, 64), blk, 0, stream>>>(
        ctx, wo_b, out, nullptr, nullptr, nullptr, nullptr, nullptr);
}

// Round 14
// 170.392 us; speedup vs baseline: 1.1307x; 1.0047x over previous
//
#include <hip/hip_runtime.h>

typedef __bf16 bf16_t;
typedef __bf16 bf16x4 __attribute__((ext_vector_type(4)));
typedef __bf16 bf16x8 __attribute__((ext_vector_type(8)));
typedef float f32x4 __attribute__((ext_vector_type(4)));
typedef unsigned int u32x2 __attribute__((ext_vector_type(2)));
typedef unsigned long long u64;

#define MFMA16(a, b, c) __builtin_amdgcn_mfma_f32_16x16x32_bf16((a), (b), (c), 0, 0, 0)

#define LDG2LDS16(g, l)                                                        \
    __builtin_amdgcn_global_load_lds(                                          \
        (const __attribute__((address_space(1))) void*)(g),                    \
        (__attribute__((address_space(3))) void*)(l), 16, 0, 0)

#if __has_builtin(__builtin_amdgcn_exp2f)
#define EXP2(x) __builtin_amdgcn_exp2f(x)
#else
#define EXP2(x) exp2f(x)
#endif

// load 8 consecutive fp32 as bf16x8
__device__ inline bf16x8 load8(const float* p) {
    const f32x4 a = *(const f32x4*)p;
    const f32x4 b = *(const f32x4*)(p + 4);
    bf16x8 r;
#pragma unroll
    for (int i = 0; i < 4; i++) { r[i] = (bf16_t)a[i]; r[4 + i] = (bf16_t)b[i]; }
    return r;
}

__device__ inline u32x2 as2(bf16x4 v) {
    u32x2 r;
    __builtin_memcpy(&r, &v, 8);
    return r;
}

// 8-byte cross-lane shuffle of a packed bf16x4 (fallback path)
__device__ inline bf16x4 shfl4(bf16x4 v, int src) {
    u64 x;
    __builtin_memcpy(&x, &v, 8);
    x = __shfl(x, src, 64);
    bf16x4 r;
    __builtin_memcpy(&r, &x, 8);
    return r;
}

// P C-layout (two bf16x4 regs covering 32 keys) -> PV B-fragment, via 6
// permlane swaps (verified algebra, rounds 0-12), ds_bpermute fallback.
__device__ inline bf16x8 p2pf(bf16x4 pb0, bf16x4 pb1, int quad, int lr) {
    bf16x8 pf;
#if __has_builtin(__builtin_amdgcn_permlane16_swap) && \
    __has_builtin(__builtin_amdgcn_permlane32_swap)
    const u32x2 P0 = as2(pb0);
    const u32x2 P1 = as2(pb1);
    const u32x2 s1a = __builtin_amdgcn_permlane16_swap(P0[0], P0[1], false, false);
    const u32x2 s1b = __builtin_amdgcn_permlane16_swap(P1[0], P1[1], false, false);
    const u32x2 s2a = __builtin_amdgcn_permlane32_swap(s1a[0], s1b[0], false, false);
    const u32x2 s2b = __builtin_amdgcn_permlane32_swap(s1a[1], s1b[1], false, false);
    const u32x2 s3a = __builtin_amdgcn_permlane16_swap(s2a[0], s2a[1], false, false);
    const u32x2 s3b = __builtin_amdgcn_permlane16_swap(s2b[0], s2b[1], false, false);
    const unsigned pfd[4] = {s3a[0], s3a[1], s3b[0], s3b[1]};
    __builtin_memcpy(&pf, pfd, 16);
#else
    const int srcLow = ((quad & 1) << 5) + lr;
    const int srcHigh = srcLow + 16;
    const bool loSel = (quad < 2);
    const bf16x4 a0 = shfl4(pb0, srcLow);
    const bf16x4 a1 = shfl4(pb1, srcLow);
    const bf16x4 b0 = shfl4(pb0, srcHigh);
    const bf16x4 b1 = shfl4(pb1, srcHigh);
    const bf16x4 lo = loSel ? a0 : a1;
    const bf16x4 hi = loSel ? b0 : b1;
#pragma unroll
    for (int r = 0; r < 4; r++) { pf[r] = lo[r]; pf[4 + r] = hi[r]; }
#endif
    return pf;
}

// ---------------------------------------------------------------------------
// fp32 -> bf16 convert: hs (4194304 el) | wqkv (3145728 el) | wo (1048576 el)
// ---------------------------------------------------------------------------
__global__ __launch_bounds__(256) void convert_kernel(const float* __restrict__ hs,
                                                      const float* __restrict__ wqkv,
                                                      const float* __restrict__ wo,
                                                      bf16_t* __restrict__ outb) {
    const size_t c = ((size_t)blockIdx.x * 256 + threadIdx.x) * 8;
    const float* src;
    size_t off;
    if (c < 4194304) { src = hs; off = c; }
    else if (c < 7340032) { src = wqkv; off = c - 4194304; }
    else { src = wo; off = c - 7340032; }
    *(bf16x8*)(outb + c) = load8(src + off);
}

// ---------------------------------------------------------------------------
// K/V swizzled layouts (MFMA-fragment order -> attn loads are base+lane*16):
//   k_sw: ((bh*128 + t>>4)*2 + (d>>5))*512 + ((t&15)+16*((d&31)>>3))*8 + (d&7)
//   v_sw: ((bh*64 + t>>5)*4 + (d>>4))*512 + ((d&15)+16*((t&31)>>3))*8 + (t&7)
// For a fixed 64-key tile kb, each of K/V occupies a CONTIGUOUS 4096-el (8 KB)
// region at base + kb*4096 -> a 128-key PAIR is a contiguous 8192-el region.
// ---------------------------------------------------------------------------

// ---------------------------------------------------------------------------
// GEMM (m97 structure, BK=32 — best measured 48.3us) + T2 XOR swizzle
// (conflicts measured 0).
// ---------------------------------------------------------------------------
template <int MODE, int NDIM, int BM>
__global__ __launch_bounds__(256) void gemm_bt(const bf16_t* __restrict__ A,
                                               const bf16_t* __restrict__ B,
                                               float* __restrict__ outp,
                                               bf16_t* __restrict__ q_ws,
                                               bf16_t* __restrict__ k_ws,
                                               bf16_t* __restrict__ v_ws,
                                               const float* __restrict__ cosb,
                                               const float* __restrict__ sinb) {
    constexpr int K = 1024;
    constexpr int IM = BM / 32;
    __shared__ __align__(16) bf16_t As[BM * 32];
    __shared__ __align__(16) bf16_t Bs[128 * 32];

    const int tid = threadIdx.x;
    const int w = tid >> 6;
    const int lane = tid & 63;
    const int lr = lane & 15;
    const int quad = lane >> 4;
    const int m0 = blockIdx.y * BM;
    const int n0 = blockIdx.x * 128;
    const int wm = (w & 1) * (BM / 2);
    const int wn = (w >> 1) * 64;

    const int srow = tid >> 2;
    // source slot pre-swizzled: slot ^ f(row), f(row) = (row>>1)&3
    const int skk = (((tid & 3) ^ ((tid >> 3) & 3)) * 8);
    const bf16_t* gA0 = A + (size_t)(m0 + srow) * K + skk;
    const bf16_t* gA1 = gA0 + (size_t)64 * K;
    const bf16_t* gB0 = B + (size_t)(n0 + srow) * K + skk;
    const bf16_t* gB1 = gB0 + (size_t)64 * K;
    bf16_t* lA0 = As + w * 512;
    bf16_t* lA1 = As + 2048 + w * 512;
    bf16_t* lB0 = Bs + w * 512;
    bf16_t* lB1 = Bs + 2048 + w * 512;

    // fragment-read slot: quad ^ f(row); row low bits = lr -> f = (lr>>1)&3
    const int qsw = (quad ^ ((lr >> 1) & 3)) * 8;

    f32x4 acc[IM][4] = {};

    for (int k0 = 0; k0 < K; k0 += 32) {
        LDG2LDS16(gA0 + k0, lA0);
        if constexpr (BM == 128) LDG2LDS16(gA1 + k0, lA1);
        LDG2LDS16(gB0 + k0, lB0);
        LDG2LDS16(gB1 + k0, lB1);
        __syncthreads();

        bf16x8 af[IM], bfm[4];
#pragma unroll
        for (int im = 0; im < IM; im++)
            af[im] = *(const bf16x8*)&As[(wm + im * 16 + lr) * 32 + qsw];
#pragma unroll
        for (int in = 0; in < 4; in++)
            bfm[in] = *(const bf16x8*)&Bs[(wn + in * 16 + lr) * 32 + qsw];
#pragma unroll
        for (int im = 0; im < IM; im++)
#pragma unroll
            for (int in = 0; in < 4; in++)
                acc[im][in] = MFMA16(af[im], bfm[in], acc[im][in]);
        __syncthreads();
    }

    if constexpr (MODE == 0) {
#pragma unroll
        for (int im = 0; im < IM; im++)
#pragma unroll
            for (int in = 0; in < 4; in++)
#pragma unroll
                for (int r = 0; r < 4; r++) {
                    const int m = m0 + wm + im * 16 + quad * 4 + r;
                    const int n = n0 + wn + in * 16 + lr;
                    outp[(size_t)m * NDIM + n] = acc[im][in][r];
                }
    } else {
        const int j = (n0 + wn) >> 6;
        if (j < 32) {
            const bool isq = (j < 16);
            const float qs = 0.125f * 1.44269504089f;
#pragma unroll
            for (int im = 0; im < IM; im++) {
#pragma unroll
                for (int r = 0; r < 4; r++) {
                    const int m = m0 + wm + im * 16 + quad * 4 + r;
                    const int b = m >> 11;
                    const int t = m & 2047;
#pragma unroll
                    for (int in = 0; in < 2; in++) {
                        const int d = in * 16 + lr;
                        const float x1 = acc[im][in][r];
                        const float x2 = acc[im][in + 2][r];
                        const float c = cosb[t * 64 + d];
                        const float s = sinb[t * 64 + d];
                        float y1 = x1 * c - x2 * s;
                        float y2 = x2 * c + x1 * s;
                        if (isq) {
                            y1 *= qs; y2 *= qs;
                            const size_t base =
                                ((size_t)(b * 16 + j) * 2048 + t) * 64 + d;
                            q_ws[base] = (bf16_t)y1;
                            q_ws[base + 32] = (bf16_t)y2;
                        } else {
                            const int bh = b * 16 + (j - 16);
                            const size_t off =
                                ((size_t)(bh * 128 + (t >> 4)) * 2) * 512 +
                                ((t & 15) + (d >> 3) * 16) * 8 + (d & 7);
                            k_ws[off] = (bf16_t)y1;
                            k_ws[off + 512] = (bf16_t)y2;
                        }
                    }
                }
            }
        } else {
#pragma unroll
            for (int im = 0; im < IM; im++)
#pragma unroll
                for (int in = 0; in < 4; in++)
#pragma unroll
                    for (int r = 0; r < 4; r++) {
                        const int m = m0 + wm + im * 16 + quad * 4 + r;
                        const int b = m >> 11;
                        const int t = m & 2047;
                        const int d = in * 16 + lr;
                        const int bh = b * 16 + (j - 32);
                        const size_t off =
                            ((size_t)(bh * 64 + (t >> 5)) * 4 + (d >> 4)) * 512 +
                            ((d & 15) + ((t & 31) >> 3) * 16) * 8 + (t & 7);
                        v_ws[off] = (bf16_t)acc[im][in][r];
                    }
        }
    }
}

// ---------------------------------------------------------------------------
// Flash attention (round 12 verified best): paired halves, 512 WGs,
// bh=blockIdx&31 L2 residency, 128-key pairs, LDS-shared K/V, hardware-
// verified sync skeleton, softmax row-sum via all-ones A-fragment MFMA
// (replaces the f32 add tree + shfl_xor reduce; denominator sums the same
// bf16-rounded P used by the PV numerator).
// ---------------------------------------------------------------------------
__global__ __launch_bounds__(256) void attn_kernel(const bf16_t* __restrict__ q_ws,
                                                   const bf16_t* __restrict__ k_ws,
                                                   const bf16_t* __restrict__ v_ws,
                                                   bf16_t* __restrict__ ctx) {
    __shared__ __align__(16) bf16_t Ks[2][8192];  // 2 x 16 KB (128-key pair)
    __shared__ __align__(16) bf16_t Vs[2][8192];  // 2 x 16 KB

    const int tid = threadIdx.x;
    const int w = tid >> 6;
    const int lane = tid & 63;
    const int lr = lane & 15;
    const int quad = lane >> 4;
    const int bh = blockIdx.x & 31;
    const int pr = blockIdx.x >> 5;  // 0..15
    const int b = bh >> 4;
    const int hd = bh & 15;

    const bf16_t* kws = k_ws + (size_t)bh * 131072;
    const bf16_t* vws = v_ws + (size_t)bh * 131072;
    const int soff = w * 512 + lane * 8;  // per-lane element offset in a sweep
    const int lo8 = lane * 8;

    bf16x8 ones8;
#pragma unroll
    for (int i = 0; i < 8; i++) ones8[i] = (bf16_t)1.0f;

    // stage a 128-key pair p (tiles 2p, 2p+1): 4(+4 if full) LDG sweeps each
#define ASTAGE2(p, buf, full)                                                  \
    {                                                                          \
        LDG2LDS16(kws + (size_t)(p) * 8192 + soff, &Ks[buf][w * 512]);         \
        LDG2LDS16(kws + (size_t)(p) * 8192 + 2048 + soff,                      \
                  &Ks[buf][2048 + w * 512]);                                   \
        LDG2LDS16(vws + (size_t)(p) * 8192 + soff, &Vs[buf][w * 512]);         \
        LDG2LDS16(vws + (size_t)(p) * 8192 + 2048 + soff,                      \
                  &Vs[buf][2048 + w * 512]);                                   \
        if (full) {                                                            \
            LDG2LDS16(kws + (size_t)(p) * 8192 + 4096 + soff,                  \
                      &Ks[buf][4096 + w * 512]);                               \
            LDG2LDS16(kws + (size_t)(p) * 8192 + 6144 + soff,                  \
                      &Ks[buf][6144 + w * 512]);                               \
            LDG2LDS16(vws + (size_t)(p) * 8192 + 4096 + soff,                  \
                      &Vs[buf][4096 + w * 512]);                               \
            LDG2LDS16(vws + (size_t)(p) * 8192 + 6144 + soff,                  \
                      &Vs[buf][6144 + w * 512]);                               \
        }                                                                      \
    }

// one 64-key subtile s (0/1) of pair in buf; key-tile index kb
#define SUBTILE(buf, s, kb)                                                    \
    {                                                                          \
        f32x4 sc[4];                                                           \
        _Pragma("unroll") for (int n = 0; n < 4; n++) {                        \
            const bf16x8 k0 =                                                  \
                *(const bf16x8*)&Ks[buf][(s) * 4096 + (2 * n) * 512 + lo8];    \
            const bf16x8 k1 =                                                  \
                *(const bf16x8*)&Ks[buf][(s) * 4096 + (2 * n + 1) * 512 + lo8];\
            const f32x4 z = {};                                                \
            sc[n] = MFMA16(k0, qlo, z);                                        \
            sc[n] = MFMA16(k1, qhi, sc[n]);                                    \
        }                                                                      \
        const int u0 = (kb) * 64;                                              \
        if ((kb) == qt) {                                                      \
            _Pragma("unroll") for (int n = 0; n < 4; n++)                      \
                _Pragma("unroll") for (int r = 0; r < 4; r++)                  \
                    if (u0 + n * 16 + quad * 4 + r > query) sc[n][r] = -1e9f;  \
        }                                                                      \
        bf16x4 pb[4];                                                          \
        _Pragma("unroll") for (int n = 0; n < 4; n++)                          \
            _Pragma("unroll") for (int r = 0; r < 4; r++)                      \
                pb[n][r] = (bf16_t)EXP2(sc[n][r]);                             \
        _Pragma("unroll") for (int hh = 0; hh < 2; hh++) {                     \
            const bf16x8 pf = p2pf(pb[2 * hh], pb[2 * hh + 1], quad, lr);      \
            lacc = MFMA16(ones8, pf, lacc);                                    \
            _Pragma("unroll") for (int n = 0; n < 4; n++) {                    \
                const bf16x8 vvf = *(const bf16x8*)                            \
                    &Vs[buf][(s) * 4096 + (hh * 4 + n) * 512 + lo8];           \
                o[n] = MFMA16(vvf, pf, o[n]);                                  \
            }                                                                  \
        }                                                                      \
    }

#pragma unroll
    for (int half = 0; half < 2; half++) {
        const int qt = half ? (31 - pr) : pr;
        const int nt = qt + 1;                // 64-key tiles
        const int npairs = (nt + 1) >> 1;     // 128-key pairs
        const int trow = qt * 64 + w * 16;
        const int query = trow + lr;

        const bf16_t* qb = q_ws + ((size_t)bh * 2048 + trow + lr) * 64 + quad * 8;
        const bf16x8 qlo = *(const bf16x8*)qb;
        const bf16x8 qhi = *(const bf16x8*)(qb + 32);

        f32x4 o[4] = {};
        f32x4 lacc = {};

        // prologue: stage pair 0 (second subtile only if it exists)
        ASTAGE2(0, 0, nt > 1);
        asm volatile("s_waitcnt vmcnt(0)" ::: "memory");
        __builtin_amdgcn_s_barrier();
        asm volatile("" ::: "memory");

        for (int i = 0; i < npairs; i++) {
            const int buf = i & 1;
            if (i + 1 < npairs)
                ASTAGE2(i + 1, buf ^ 1, (2 * (i + 1) + 1) < nt);

            SUBTILE(buf, 0, 2 * i);
            if (2 * i + 1 < nt) SUBTILE(buf, 1, 2 * i + 1);

            // all LDS reads of buf done; this wave's stage loads landed
            asm volatile("s_waitcnt lgkmcnt(0) vmcnt(0)" ::: "memory");
            __builtin_amdgcn_s_barrier();
            asm volatile("" ::: "memory");
        }

        // lacc rows are all equal to sum_k P[k][query] -> take reg 0.
        const float inv = 1.0f / fmaxf(lacc[0], 1e-30f);
        const size_t base = ((size_t)b * 2048 + query) * 1024 + hd * 64 + quad * 4;
#pragma unroll
        for (int n = 0; n < 4; n++) {
            bf16x4 ob;
#pragma unroll
            for (int r = 0; r < 4; r++) ob[r] = (bf16_t)(o[n][r] * inv);
            *(bf16x4*)&ctx[base + n * 16] = ob;
        }
    }
#undef ASTAGE2
#undef SUBTILE
}

// ---------------------------------------------------------------------------
// Launcher. Inputs fp32, output fp32.
// ws bytes: [0,8M) hs_b -> (after gemm1) ctx overlay | [8M,14M) wqkv_b |
//           [14M,16M) wo_b | [16M,24M) q | [24M,32M) k | [32M,40M) v.
// ---------------------------------------------------------------------------
extern "C" void kernel_launch(void* const* d_in, const int* in_sizes, int n_in,
                              void* d_out, int out_size, void* d_ws, size_t ws_size,
                              hipStream_t stream) {
    const float* hs = (const float*)d_in[0];
    const float* cosb = (const float*)d_in[1];
    const float* sinb = (const float*)d_in[2];
    const float* wqkv = (const float*)d_in[3];
    const float* wo = (const float*)d_in[4];
    float* out = (float*)d_out;

    char* ws = (char*)d_ws;
    bf16_t* hs_b = (bf16_t*)(ws);
    bf16_t* wqkv_b = hs_b + 4194304;
    bf16_t* wo_b = hs_b + 7340032;
    bf16_t* q_ws = (bf16_t*)(ws + (size_t)(16u << 20));
    bf16_t* k_ws = (bf16_t*)(ws + (size_t)(24u << 20));
    bf16_t* v_ws = (bf16_t*)(ws + (size_t)(32u << 20));
    bf16_t* ctx = (bf16_t*)(ws);  // overlays hs_b (dead after gemm1)

    const dim3 blk(256);

    // 0) fp32 -> bf16 convert (hs | wqkv | wo packed)
    convert_kernel<<<dim3(4096), blk, 0, stream>>>(hs, wqkv, wo, hs_b);

    // 1) QKV projection + fused RoPE + scatter: M=4096, N=3072, K=1024
    gemm_bt<1, 3072, 128><<<dim3(24, 32), blk, 0, stream>>>(
        hs_b, wqkv_b, nullptr, q_ws, k_ws, v_ws, cosb, sinb);

    // 2) Flash attention (paired halves, 128-key pairs, ones-MFMA row-sum)
    attn_kernel<<<dim3(512), blk, 0, stream>>>(q_ws, k_ws, v_ws, ctx);

    // 3) Output projection: M=4096, N=1024, K=1024 (BM=64 -> 512 blocks)
    gemm_bt<0, 1024, 64><<<dim3(8, 64), blk, 0, stream>>>(
        ctx, wo_b, out, nullptr, nullptr, nullptr, nullptr, nullptr);
}

// Round 15
// 164.799 us; speedup vs baseline: 1.1691x; 1.0339x over previous
//
#include <hip/hip_runtime.h>

typedef __bf16 bf16_t;
typedef __bf16 bf16x4 __attribute__((ext_vector_type(4)));
typedef __bf16 bf16x8 __attribute__((ext_vector_type(8)));
typedef float f32x4 __attribute__((ext_vector_type(4)));
typedef unsigned int u32x2 __attribute__((ext_vector_type(2)));
typedef unsigned long long u64;

#define MFMA16(a, b, c) __builtin_amdgcn_mfma_f32_16x16x32_bf16((a), (b), (c), 0, 0, 0)

#define LDG2LDS16(g, l)                                                        \
    __builtin_amdgcn_global_load_lds(                                          \
        (const __attribute__((address_space(1))) void*)(g),                    \
        (__attribute__((address_space(3))) void*)(l), 16, 0, 0)

#if __has_builtin(__builtin_amdgcn_exp2f)
#define EXP2(x) __builtin_amdgcn_exp2f(x)
#else
#define EXP2(x) exp2f(x)
#endif

// load 8 consecutive fp32 as bf16x8
__device__ inline bf16x8 load8(const float* p) {
    const f32x4 a = *(const f32x4*)p;
    const f32x4 b = *(const f32x4*)(p + 4);
    bf16x8 r;
#pragma unroll
    for (int i = 0; i < 4; i++) { r[i] = (bf16_t)a[i]; r[4 + i] = (bf16_t)b[i]; }
    return r;
}

__device__ inline u32x2 as2(bf16x4 v) {
    u32x2 r;
    __builtin_memcpy(&r, &v, 8);
    return r;
}

// 8-byte cross-lane shuffle of a packed bf16x4 (fallback path)
__device__ inline bf16x4 shfl4(bf16x4 v, int src) {
    u64 x;
    __builtin_memcpy(&x, &v, 8);
    x = __shfl(x, src, 64);
    bf16x4 r;
    __builtin_memcpy(&r, &x, 8);
    return r;
}

// P C-layout (two bf16x4 regs covering 32 keys) -> PV B-fragment, via 6
// permlane swaps (verified algebra, rounds 0-14), ds_bpermute fallback.
__device__ inline bf16x8 p2pf(bf16x4 pb0, bf16x4 pb1, int quad, int lr) {
    bf16x8 pf;
#if __has_builtin(__builtin_amdgcn_permlane16_swap) && \
    __has_builtin(__builtin_amdgcn_permlane32_swap)
    const u32x2 P0 = as2(pb0);
    const u32x2 P1 = as2(pb1);
    const u32x2 s1a = __builtin_amdgcn_permlane16_swap(P0[0], P0[1], false, false);
    const u32x2 s1b = __builtin_amdgcn_permlane16_swap(P1[0], P1[1], false, false);
    const u32x2 s2a = __builtin_amdgcn_permlane32_swap(s1a[0], s1b[0], false, false);
    const u32x2 s2b = __builtin_amdgcn_permlane32_swap(s1a[1], s1b[1], false, false);
    const u32x2 s3a = __builtin_amdgcn_permlane16_swap(s2a[0], s2a[1], false, false);
    const u32x2 s3b = __builtin_amdgcn_permlane16_swap(s2b[0], s2b[1], false, false);
    const unsigned pfd[4] = {s3a[0], s3a[1], s3b[0], s3b[1]};
    __builtin_memcpy(&pf, pfd, 16);
#else
    const int srcLow = ((quad & 1) << 5) + lr;
    const int srcHigh = srcLow + 16;
    const bool loSel = (quad < 2);
    const bf16x4 a0 = shfl4(pb0, srcLow);
    const bf16x4 a1 = shfl4(pb1, srcLow);
    const bf16x4 b0 = shfl4(pb0, srcHigh);
    const bf16x4 b1 = shfl4(pb1, srcHigh);
    const bf16x4 lo = loSel ? a0 : a1;
    const bf16x4 hi = loSel ? b0 : b1;
#pragma unroll
    for (int r = 0; r < 4; r++) { pf[r] = lo[r]; pf[4 + r] = hi[r]; }
#endif
    return pf;
}

// ---------------------------------------------------------------------------
// fp32 -> bf16 convert: hs (4194304 el) | wqkv (3145728 el) | wo (1048576 el)
// ---------------------------------------------------------------------------
__global__ __launch_bounds__(256) void convert_kernel(const float* __restrict__ hs,
                                                      const float* __restrict__ wqkv,
                                                      const float* __restrict__ wo,
                                                      bf16_t* __restrict__ outb) {
    const size_t c = ((size_t)blockIdx.x * 256 + threadIdx.x) * 8;
    const float* src;
    size_t off;
    if (c < 4194304) { src = hs; off = c; }
    else if (c < 7340032) { src = wqkv; off = c - 4194304; }
    else { src = wo; off = c - 7340032; }
    *(bf16x8*)(outb + c) = load8(src + off);
}

// ---------------------------------------------------------------------------
// K/V swizzled layouts (MFMA-fragment order -> attn loads are base+lane*16):
//   k_sw: ((bh*128 + t>>4)*2 + (d>>5))*512 + ((t&15)+16*((d&31)>>3))*8 + (d&7)
//   v_sw: ((bh*64 + t>>5)*4 + (d>>4))*512 + ((d&15)+16*((t&31)>>3))*8 + (t&7)
// For a fixed 64-key tile kb, each of K/V occupies a CONTIGUOUS 4096-el (8 KB)
// region at base + kb*4096 -> stageable with 2 global_load_lds sweeps.
// ---------------------------------------------------------------------------

// ---------------------------------------------------------------------------
// GEMM (m97 structure, BK=32 — best measured) + T2 XOR swizzle
// (conflicts measured 0). Unchanged from round 14 (verified).
// ---------------------------------------------------------------------------
template <int MODE, int NDIM, int BM>
__global__ __launch_bounds__(256) void gemm_bt(const bf16_t* __restrict__ A,
                                               const bf16_t* __restrict__ B,
                                               float* __restrict__ outp,
                                               bf16_t* __restrict__ q_ws,
                                               bf16_t* __restrict__ k_ws,
                                               bf16_t* __restrict__ v_ws,
                                               const float* __restrict__ cosb,
                                               const float* __restrict__ sinb) {
    constexpr int K = 1024;
    constexpr int IM = BM / 32;
    __shared__ __align__(16) bf16_t As[BM * 32];
    __shared__ __align__(16) bf16_t Bs[128 * 32];

    const int tid = threadIdx.x;
    const int w = tid >> 6;
    const int lane = tid & 63;
    const int lr = lane & 15;
    const int quad = lane >> 4;
    const int m0 = blockIdx.y * BM;
    const int n0 = blockIdx.x * 128;
    const int wm = (w & 1) * (BM / 2);
    const int wn = (w >> 1) * 64;

    const int srow = tid >> 2;
    // source slot pre-swizzled: slot ^ f(row), f(row) = (row>>1)&3
    const int skk = (((tid & 3) ^ ((tid >> 3) & 3)) * 8);
    const bf16_t* gA0 = A + (size_t)(m0 + srow) * K + skk;
    const bf16_t* gA1 = gA0 + (size_t)64 * K;
    const bf16_t* gB0 = B + (size_t)(n0 + srow) * K + skk;
    const bf16_t* gB1 = gB0 + (size_t)64 * K;
    bf16_t* lA0 = As + w * 512;
    bf16_t* lA1 = As + 2048 + w * 512;
    bf16_t* lB0 = Bs + w * 512;
    bf16_t* lB1 = Bs + 2048 + w * 512;

    // fragment-read slot: quad ^ f(row); row low bits = lr -> f = (lr>>1)&3
    const int qsw = (quad ^ ((lr >> 1) & 3)) * 8;

    f32x4 acc[IM][4] = {};

    for (int k0 = 0; k0 < K; k0 += 32) {
        LDG2LDS16(gA0 + k0, lA0);
        if constexpr (BM == 128) LDG2LDS16(gA1 + k0, lA1);
        LDG2LDS16(gB0 + k0, lB0);
        LDG2LDS16(gB1 + k0, lB1);
        __syncthreads();

        bf16x8 af[IM], bfm[4];
#pragma unroll
        for (int im = 0; im < IM; im++)
            af[im] = *(const bf16x8*)&As[(wm + im * 16 + lr) * 32 + qsw];
#pragma unroll
        for (int in = 0; in < 4; in++)
            bfm[in] = *(const bf16x8*)&Bs[(wn + in * 16 + lr) * 32 + qsw];
#pragma unroll
        for (int im = 0; im < IM; im++)
#pragma unroll
            for (int in = 0; in < 4; in++)
                acc[im][in] = MFMA16(af[im], bfm[in], acc[im][in]);
        __syncthreads();
    }

    if constexpr (MODE == 0) {
#pragma unroll
        for (int im = 0; im < IM; im++)
#pragma unroll
            for (int in = 0; in < 4; in++)
#pragma unroll
                for (int r = 0; r < 4; r++) {
                    const int m = m0 + wm + im * 16 + quad * 4 + r;
                    const int n = n0 + wn + in * 16 + lr;
                    outp[(size_t)m * NDIM + n] = acc[im][in][r];
                }
    } else {
        const int j = (n0 + wn) >> 6;
        if (j < 32) {
            const bool isq = (j < 16);
            const float qs = 0.125f * 1.44269504089f;
#pragma unroll
            for (int im = 0; im < IM; im++) {
#pragma unroll
                for (int r = 0; r < 4; r++) {
                    const int m = m0 + wm + im * 16 + quad * 4 + r;
                    const int b = m >> 11;
                    const int t = m & 2047;
#pragma unroll
                    for (int in = 0; in < 2; in++) {
                        const int d = in * 16 + lr;
                        const float x1 = acc[im][in][r];
                        const float x2 = acc[im][in + 2][r];
                        const float c = cosb[t * 64 + d];
                        const float s = sinb[t * 64 + d];
                        float y1 = x1 * c - x2 * s;
                        float y2 = x2 * c + x1 * s;
                        if (isq) {
                            y1 *= qs; y2 *= qs;
                            const size_t base =
                                ((size_t)(b * 16 + j) * 2048 + t) * 64 + d;
                            q_ws[base] = (bf16_t)y1;
                            q_ws[base + 32] = (bf16_t)y2;
                        } else {
                            const int bh = b * 16 + (j - 16);
                            const size_t off =
                                ((size_t)(bh * 128 + (t >> 4)) * 2) * 512 +
                                ((t & 15) + (d >> 3) * 16) * 8 + (d & 7);
                            k_ws[off] = (bf16_t)y1;
                            k_ws[off + 512] = (bf16_t)y2;
                        }
                    }
                }
            }
        } else {
#pragma unroll
            for (int im = 0; im < IM; im++)
#pragma unroll
                for (int in = 0; in < 4; in++)
#pragma unroll
                    for (int r = 0; r < 4; r++) {
                        const int m = m0 + wm + im * 16 + quad * 4 + r;
                        const int b = m >> 11;
                        const int t = m & 2047;
                        const int d = in * 16 + lr;
                        const int bh = b * 16 + (j - 32);
                        const size_t off =
                            ((size_t)(bh * 64 + (t >> 5)) * 4 + (d >> 4)) * 512 +
                            ((d & 15) + ((t & 31) >> 3) * 16) * 8 + (t & 7);
                        v_ws[off] = (bf16_t)acc[im][in][r];
                    }
        }
    }
}

// ---------------------------------------------------------------------------
// Flash attention (round 15): 512 threads / 8 waves per WG. Waves 0-3 compute
// qtA = pr, waves 4-7 compute qtB = 31-pr, CONCURRENTLY sharing one K/V LDS
// stream (waves 0-3 stage K, waves 4-7 stage V): each staged tile feeds 128
// queries instead of 64 -> staging + L2 traffic -26% (tiles/WG 33 -> 32-pr),
// and 16 waves/CU (vs 8) hide the exp2 chain. Complementary pr-fold
// pr(g)+pr(g+8)=15 keeps co-resident WG-pair work constant (49 iters);
// bh = blockIdx&31 keeps the 4-streams/XCD L2 residency (r8 lesson).
// Sync skeleton is the r7/r12/r14-verified shape verbatim: stage(kb+1) at
// loop top into other buffer, wave-uniform compute guard (kb <= qtw), one
// lgkmcnt(0)+vmcnt(0)+s_barrier per iteration, identical barrier count for
// all 8 waves. SUBTILE body (ones-MFMA lacc row-sum) byte-copied from the
// round-14 passing kernel.
// LDS 32 KB/WG -> 2 WGs/CU; VGPR ~112 <= 128 cap from launch_bounds(512,4).
// ---------------------------------------------------------------------------
__global__ __launch_bounds__(512, 4) void attn_kernel(const bf16_t* __restrict__ q_ws,
                                                      const bf16_t* __restrict__ k_ws,
                                                      const bf16_t* __restrict__ v_ws,
                                                      bf16_t* __restrict__ ctx) {
    __shared__ __align__(16) bf16_t Ks[2][4096];  // 2 x 8 KB
    __shared__ __align__(16) bf16_t Vs[2][4096];  // 2 x 8 KB

    const int tid = threadIdx.x;
    const int w = tid >> 6;        // 0..7
    const int wq = w & 3;          // quad-wave index within half
    const int lane = tid & 63;
    const int lr = lane & 15;
    const int quad = lane >> 4;
    const int bh = blockIdx.x & 31;
    const int g = blockIdx.x >> 5;               // 0..15
    const int pr = (g < 8) ? g : 23 - g;         // pr(g)+pr(g+8)=15, bijective
    const int qtA = pr;
    const int qtB = 31 - pr;
    const int qtw = (w < 4) ? qtA : qtB;         // this wave's query tile
    const int b = bh >> 4;
    const int hd = bh & 15;

    const bf16_t* kws = k_ws + (size_t)bh * 131072;
    const bf16_t* vws = v_ws + (size_t)bh * 131072;
    const int soff = wq * 512 + lane * 8;  // per-lane element offset in sweep
    const int lo8 = lane * 8;

    bf16x8 ones8;
#pragma unroll
    for (int i = 0; i < 8; i++) ones8[i] = (bf16_t)1.0f;

    // waves 0-3 stage the K tile (2 sweeps each), waves 4-7 the V tile.
#define ASTAGE(kb, bufi)                                                       \
    {                                                                          \
        if (w < 4) {                                                           \
            LDG2LDS16(kws + (size_t)(kb) * 4096 + soff, &Ks[bufi][wq * 512]);  \
            LDG2LDS16(kws + (size_t)(kb) * 4096 + 2048 + soff,                 \
                      &Ks[bufi][2048 + wq * 512]);                             \
        } else {                                                               \
            LDG2LDS16(vws + (size_t)(kb) * 4096 + soff, &Vs[bufi][wq * 512]);  \
            LDG2LDS16(vws + (size_t)(kb) * 4096 + 2048 + soff,                 \
                      &Vs[bufi][2048 + wq * 512]);                             \
        }                                                                      \
    }

    const int trow = qtw * 64 + wq * 16;
    const int query = trow + lr;

    const bf16_t* qb = q_ws + ((size_t)bh * 2048 + trow + lr) * 64 + quad * 8;
    const bf16x8 qlo = *(const bf16x8*)qb;
    const bf16x8 qhi = *(const bf16x8*)(qb + 32);

    f32x4 o[4] = {};
    f32x4 lacc = {};

    // prologue: stage tile 0
    ASTAGE(0, 0);
    asm volatile("s_waitcnt vmcnt(0)" ::: "memory");
    __builtin_amdgcn_s_barrier();
    asm volatile("" ::: "memory");

    for (int kb = 0; kb <= qtB; kb++) {
        const int bufi = kb & 1;
        if (kb < qtB) ASTAGE(kb + 1, bufi ^ 1);

        if (kb <= qtw) {  // wave-uniform guard; barriers stay outside
            // ---- QK^T from LDS ----
            f32x4 s[4];
#pragma unroll
            for (int n = 0; n < 4; n++) {
                const bf16x8 k0 = *(const bf16x8*)&Ks[bufi][(2 * n) * 512 + lo8];
                const bf16x8 k1 =
                    *(const bf16x8*)&Ks[bufi][(2 * n + 1) * 512 + lo8];
                const f32x4 z = {};
                s[n] = MFMA16(k0, qlo, z);
                s[n] = MFMA16(k1, qhi, s[n]);
            }

            const int u0 = kb * 64;
            if (kb == qtw) {  // diagonal: causal mask (key > query)
#pragma unroll
                for (int n = 0; n < 4; n++)
#pragma unroll
                    for (int r = 0; r < 4; r++)
                        if (u0 + n * 16 + quad * 4 + r > query) s[n][r] = -1e9f;
            }

            bf16x4 pb[4];
#pragma unroll
            for (int n = 0; n < 4; n++)
#pragma unroll
                for (int r = 0; r < 4; r++) pb[n][r] = (bf16_t)EXP2(s[n][r]);

#pragma unroll
            for (int hh = 0; hh < 2; hh++) {  // 32-key halves
                const bf16x8 pf = p2pf(pb[2 * hh], pb[2 * hh + 1], quad, lr);
                lacc = MFMA16(ones8, pf, lacc);
#pragma unroll
                for (int n = 0; n < 4; n++) {
                    const bf16x8 vvf =
                        *(const bf16x8*)&Vs[bufi][(hh * 4 + n) * 512 + lo8];
                    o[n] = MFMA16(vvf, pf, o[n]);
                }
            }
        }

        // all LDS reads of bufi done; this wave's stage loads landed
        asm volatile("s_waitcnt lgkmcnt(0) vmcnt(0)" ::: "memory");
        __builtin_amdgcn_s_barrier();
        asm volatile("" ::: "memory");
    }

    // lacc rows are all equal to sum_k P[k][query] -> take reg 0.
    const float inv = 1.0f / fmaxf(lacc[0], 1e-30f);
    const size_t base = ((size_t)b * 2048 + query) * 1024 + hd * 64 + quad * 4;
#pragma unroll
    for (int n = 0; n < 4; n++) {
        bf16x4 ob;
#pragma unroll
        for (int r = 0; r < 4; r++) ob[r] = (bf16_t)(o[n][r] * inv);
        *(bf16x4*)&ctx[base + n * 16] = ob;
    }
#undef ASTAGE
}

// ---------------------------------------------------------------------------
// Launcher. Inputs fp32, output fp32.
// ws bytes: [0,8M) hs_b -> (after gemm1) ctx overlay | [8M,14M) wqkv_b |
//           [14M,16M) wo_b | [16M,24M) q | [24M,32M) k | [32M,40M) v.
// ---------------------------------------------------------------------------
extern "C" void kernel_launch(void* const* d_in, const int* in_sizes, int n_in,
                              void* d_out, int out_size, void* d_ws, size_t ws_size,
                              hipStream_t stream) {
    const float* hs = (const float*)d_in[0];
    const float* cosb = (const float*)d_in[1];
    const float* sinb = (const float*)d_in[2];
    const float* wqkv = (const float*)d_in[3];
    const float* wo = (const float*)d_in[4];
    float* out = (float*)d_out;

    char* ws = (char*)d_ws;
    bf16_t* hs_b = (bf16_t*)(ws);
    bf16_t* wqkv_b = hs_b + 4194304;
    bf16_t* wo_b = hs_b + 7340032;
    bf16_t* q_ws = (bf16_t*)(ws + (size_t)(16u << 20));
    bf16_t* k_ws = (bf16_t*)(ws + (size_t)(24u << 20));
    bf16_t* v_ws = (bf16_t*)(ws + (size_t)(32u << 20));
    bf16_t* ctx = (bf16_t*)(ws);  // overlays hs_b (dead after gemm1)

    const dim3 blk(256);

    // 0) fp32 -> bf16 convert (hs | wqkv | wo packed)
    convert_kernel<<<dim3(4096), blk, 0, stream>>>(hs, wqkv, wo, hs_b);

    // 1) QKV projection + fused RoPE + scatter: M=4096, N=3072, K=1024
    gemm_bt<1, 3072, 128><<<dim3(24, 32), blk, 0, stream>>>(
        hs_b, wqkv_b, nullptr, q_ws, k_ws, v_ws, cosb, sinb);

    // 2) Flash attention (8-wave shared K/V stream, concurrent halves)
    attn_kernel<<<dim3(512), dim3(512), 0, stream>>>(q_ws, k_ws, v_ws, ctx);

    // 3) Output projection: M=4096, N=1024, K=1024 (BM=64 -> 512 blocks)
    gemm_bt<0, 1024, 64><<<dim3(8, 64), blk, 0, stream>>>(
        ctx, wo_b, out, nullptr, nullptr, nullptr, nullptr, nullptr);
}